// Round 1
// baseline (1442.866 us; speedup 1.0000x reference)
//
#include <hip/hip_runtime.h>
#include <math.h>

#define HID 128

// ---------------------------------------------------------------------------
// Kernel 1: node feature encode: feats(160) @ proj_W(160x128) + proj_b
// block = 128 threads (thread j = output dim j), 8 nodes per iteration
// ---------------------------------------------------------------------------
__global__ __launch_bounds__(128) void encode_kernel(
    const int* __restrict__ type_idx, const int* __restrict__ cat_idx,
    const float* __restrict__ log_deg,
    const float* __restrict__ type_embed, const float* __restrict__ cat0,
    const float* __restrict__ cat1, const float* __restrict__ deg_W,
    const float* __restrict__ deg_b, const float* __restrict__ proj_W,
    const float* __restrict__ proj_b, float* __restrict__ x, int n)
{
    __shared__ float feats[8][160];   // 160*4 = 640 B row stride, 16B aligned
    const int j = threadIdx.x;
    for (int base = blockIdx.x * 8; base < n; base += gridDim.x * 8) {
        const int nbc = min(8, n - base);
        for (int nb = 0; nb < nbc; ++nb) {
            const int node = base + nb;
            if (j < 64) {
                const int t = type_idx[node];
                feats[nb][j] = type_embed[t * 64 + j];
            } else if (j < 96) {
                const int c0 = cat_idx[node * 2 + 0];
                feats[nb][j] = cat0[c0 * 32 + (j - 64)];
            } else {
                const int c1 = cat_idx[node * 2 + 1];
                feats[nb][j] = cat1[c1 * 32 + (j - 96)];
            }
            if (j < 32) {
                const float ld = log_deg[node];
                feats[nb][128 + j] = fmaxf(ld * deg_W[j] + deg_b[j], 0.0f);
            }
        }
        __syncthreads();
        float acc[8];
        #pragma unroll
        for (int nb = 0; nb < 8; ++nb) acc[nb] = 0.0f;
        for (int i = 0; i < 160; i += 4) {
            float w[4];
            #pragma unroll
            for (int t = 0; t < 4; ++t) w[t] = proj_W[(i + t) * 128 + j];
            #pragma unroll
            for (int nb = 0; nb < 8; ++nb) {
                const float4 v = *(const float4*)&feats[nb][i];
                acc[nb] += v.x * w[0] + v.y * w[1] + v.z * w[2] + v.w * w[3];
            }
        }
        const float b = proj_b[j];
        for (int nb = 0; nb < nbc; ++nb)
            x[(size_t)(base + nb) * HID + j] = acc[nb] + b;
        __syncthreads();
    }
}

// ---------------------------------------------------------------------------
// Kernel 2: qkv = x @ Wqkv(128x384) + bqkv.  block = 128 threads, 8 nodes/iter
// thread j computes out dims j, j+128, j+256.
// ---------------------------------------------------------------------------
__global__ __launch_bounds__(128) void qkv_kernel(
    const float* __restrict__ x, const float* __restrict__ W,
    const float* __restrict__ b, float* __restrict__ qkv, int n)
{
    __shared__ float xs[8][HID];
    const int j = threadIdx.x;
    for (int base = blockIdx.x * 8; base < n; base += gridDim.x * 8) {
        const int nbc = min(8, n - base);
        for (int nb = 0; nb < nbc; ++nb)
            xs[nb][j] = x[(size_t)(base + nb) * HID + j];
        __syncthreads();
        float a0[8], a1[8], a2[8];
        #pragma unroll
        for (int nb = 0; nb < 8; ++nb) { a0[nb] = 0.f; a1[nb] = 0.f; a2[nb] = 0.f; }
        for (int i = 0; i < 128; i += 4) {
            float w0[4], w1[4], w2[4];
            #pragma unroll
            for (int t = 0; t < 4; ++t) {
                w0[t] = W[(i + t) * 384 + j];
                w1[t] = W[(i + t) * 384 + 128 + j];
                w2[t] = W[(i + t) * 384 + 256 + j];
            }
            #pragma unroll
            for (int nb = 0; nb < 8; ++nb) {
                const float4 v = *(const float4*)&xs[nb][i];
                a0[nb] += v.x * w0[0] + v.y * w0[1] + v.z * w0[2] + v.w * w0[3];
                a1[nb] += v.x * w1[0] + v.y * w1[1] + v.z * w1[2] + v.w * w1[3];
                a2[nb] += v.x * w2[0] + v.y * w2[1] + v.z * w2[2] + v.w * w2[3];
            }
        }
        const float bb0 = b[j], bb1 = b[128 + j], bb2 = b[256 + j];
        for (int nb = 0; nb < nbc; ++nb) {
            float* o = qkv + (size_t)(base + nb) * 384;
            o[j]       = a0[nb] + bb0;
            o[128 + j] = a1[nb] + bb1;
            o[256 + j] = a2[nb] + bb2;
        }
        __syncthreads();
    }
}

// ---------------------------------------------------------------------------
// Kernel 3: local attention (C = self + 16 nbrs) + output projection + relu.
// block = 256 (4 waves); wave per node-group of 4.
// lane = head*16 + sub; lane covers dims (2*sub, 2*sub+1) of its head.
// ---------------------------------------------------------------------------
__global__ __launch_bounds__(256) void attn_kernel(
    const float* __restrict__ qkv, const float* __restrict__ x_in,
    const int* __restrict__ nbr_idx, const int* __restrict__ nbr_mask,
    const float* __restrict__ Wo, const float* __restrict__ bo,
    float* __restrict__ x_out, int n)
{
    __shared__ float o_s[4][4][HID];     // [wave][nb][dim], per-wave private
    const int wave = threadIdx.x >> 6;
    const int lane = threadIdx.x & 63;
    const int head = lane >> 4;
    const int sub  = lane & 15;
    const float scale = 0.17677669529663687f;   // 1/sqrt(32)
    const int gw = blockIdx.x * 4 + wave;
    const int stride = gridDim.x * 4 * 4;
    for (int base = gw * 4; base < n; base += stride) {
        const int nbc = min(4, n - base);
        int hasn[4] = {0, 0, 0, 0};
        for (int nb = 0; nb < nbc; ++nb) {
            const int node = base + nb;
            const float2 q = *(const float2*)(qkv + (size_t)node * 384 + head * 32 + sub * 2);
            float s[17];
            int cix[17];
            int anyn = 0;
            #pragma unroll
            for (int c = 0; c < 17; ++c) {
                int cidx, valid;
                if (c == 0) { cidx = node; valid = 1; }
                else {
                    cidx  = nbr_idx[node * 16 + (c - 1)];
                    valid = nbr_mask[node * 16 + (c - 1)];
                    anyn |= valid;
                }
                cix[c] = cidx;
                const float2 k = *(const float2*)(qkv + (size_t)cidx * 384 + 128 + head * 32 + sub * 2);
                float p = q.x * k.x + q.y * k.y;
                p += __shfl_xor(p, 1);
                p += __shfl_xor(p, 2);
                p += __shfl_xor(p, 4);
                p += __shfl_xor(p, 8);
                s[c] = valid ? p * scale : -1e9f;
            }
            hasn[nb] = anyn;
            float mx = s[0];
            #pragma unroll
            for (int c = 1; c < 17; ++c) mx = fmaxf(mx, s[c]);
            float sum = 0.0f;
            #pragma unroll
            for (int c = 0; c < 17; ++c) { s[c] = __expf(s[c] - mx); sum += s[c]; }
            const float inv = 1.0f / sum;
            float ox = 0.0f, oy = 0.0f;
            #pragma unroll
            for (int c = 0; c < 17; ++c) {
                const float2 v = *(const float2*)(qkv + (size_t)cix[c] * 384 + 256 + head * 32 + sub * 2);
                const float a = s[c] * inv;
                ox += a * v.x;
                oy += a * v.y;
            }
            // dim offset head*32 + 2*sub == 2*lane
            *(float2*)&o_s[wave][nb][lane * 2] = make_float2(ox, oy);
        }
        // same-wave producer/consumer on o_s: no __syncthreads needed
        float acc0[4] = {0.f, 0.f, 0.f, 0.f};
        float acc1[4] = {0.f, 0.f, 0.f, 0.f};
        for (int i = 0; i < 128; i += 4) {
            float w0[4], w1[4];
            #pragma unroll
            for (int t = 0; t < 4; ++t) {
                w0[t] = Wo[(i + t) * HID + lane];
                w1[t] = Wo[(i + t) * HID + 64 + lane];
            }
            #pragma unroll
            for (int nb = 0; nb < 4; ++nb) {
                const float4 v = *(const float4*)&o_s[wave][nb][i];
                acc0[nb] += v.x * w0[0] + v.y * w0[1] + v.z * w0[2] + v.w * w0[3];
                acc1[nb] += v.x * w1[0] + v.y * w1[1] + v.z * w1[2] + v.w * w1[3];
            }
        }
        const float b0 = bo[lane], b1 = bo[64 + lane];
        for (int nb = 0; nb < nbc; ++nb) {
            const int node = base + nb;
            float r0 = acc0[nb] + b0;
            float r1 = acc1[nb] + b1;
            if (!hasn[nb]) {             // wave-uniform branch
                r0 = x_in[(size_t)node * HID + lane];
                r1 = x_in[(size_t)node * HID + 64 + lane];
            }
            x_out[(size_t)node * HID + lane]      = fmaxf(r0, 0.0f);
            x_out[(size_t)node * HID + 64 + lane] = fmaxf(r1, 0.0f);
        }
    }
}

// ---------------------------------------------------------------------------
// Kernel 4: edge MLP  concat(x[e0], x[e1], ef) (258) ->128 relu ->64 relu ->1
// block = 256 (4 waves); wave per edge-group of 8.
// Layer1: lane computes out dims (lane, lane+64). Layer2: out dim lane (64).
// ---------------------------------------------------------------------------
__global__ __launch_bounds__(256) void edge_kernel(
    const float* __restrict__ x, const int* __restrict__ edges,
    const float* __restrict__ edge_feats,
    const float* __restrict__ W1, const float* __restrict__ b1,
    const float* __restrict__ W2, const float* __restrict__ b2,
    const float* __restrict__ W3, const float* __restrict__ b3,
    float* __restrict__ out, int ne)
{
    __shared__ float in_s[4][8][260];    // 260 pad -> 1040 B row, 16B aligned
    __shared__ float h1s[4][8][HID];
    const int wave = threadIdx.x >> 6;
    const int lane = threadIdx.x & 63;
    const int gw = blockIdx.x * 4 + wave;
    const int stride = gridDim.x * 4 * 8;
    for (int base = gw * 8; base < ne; base += stride) {
        const int ebc = min(8, ne - base);
        for (int nb = 0; nb < ebc; ++nb) {
            const int e  = base + nb;
            const int e0 = edges[e * 2 + 0];
            const int e1 = edges[e * 2 + 1];
            *(float2*)&in_s[wave][nb][lane * 2] =
                *(const float2*)(x + (size_t)e0 * HID + lane * 2);
            *(float2*)&in_s[wave][nb][128 + lane * 2] =
                *(const float2*)(x + (size_t)e1 * HID + lane * 2);
            if (lane == 0) {
                in_s[wave][nb][256] = edge_feats[(size_t)e * 2 + 0];
                in_s[wave][nb][257] = edge_feats[(size_t)e * 2 + 1];
            }
        }
        // layer 1: 258 -> 128
        float a0[8], a1[8];
        #pragma unroll
        for (int nb = 0; nb < 8; ++nb) { a0[nb] = 0.f; a1[nb] = 0.f; }
        for (int i = 0; i < 256; i += 4) {
            float w0[4], w1[4];
            #pragma unroll
            for (int t = 0; t < 4; ++t) {
                w0[t] = W1[(i + t) * 128 + lane];
                w1[t] = W1[(i + t) * 128 + 64 + lane];
            }
            #pragma unroll
            for (int nb = 0; nb < 8; ++nb) {
                const float4 v = *(const float4*)&in_s[wave][nb][i];
                a0[nb] += v.x * w0[0] + v.y * w0[1] + v.z * w0[2] + v.w * w0[3];
                a1[nb] += v.x * w1[0] + v.y * w1[1] + v.z * w1[2] + v.w * w1[3];
            }
        }
        {   // i = 256, 257 (edge feats)
            const float w0a = W1[256 * 128 + lane], w1a = W1[256 * 128 + 64 + lane];
            const float w0b = W1[257 * 128 + lane], w1b = W1[257 * 128 + 64 + lane];
            #pragma unroll
            for (int nb = 0; nb < 8; ++nb) {
                const float2 v = *(const float2*)&in_s[wave][nb][256];
                a0[nb] += v.x * w0a + v.y * w0b;
                a1[nb] += v.x * w1a + v.y * w1b;
            }
        }
        const float bb1_0 = b1[lane], bb1_1 = b1[64 + lane];
        for (int nb = 0; nb < ebc; ++nb) {
            h1s[wave][nb][lane]      = fmaxf(a0[nb] + bb1_0, 0.0f);
            h1s[wave][nb][64 + lane] = fmaxf(a1[nb] + bb1_1, 0.0f);
        }
        // layer 2: 128 -> 64 (lane = out dim)
        float a2[8];
        #pragma unroll
        for (int nb = 0; nb < 8; ++nb) a2[nb] = 0.f;
        for (int i = 0; i < 128; i += 4) {
            float w[4];
            #pragma unroll
            for (int t = 0; t < 4; ++t) w[t] = W2[(i + t) * 64 + lane];
            #pragma unroll
            for (int nb = 0; nb < 8; ++nb) {
                const float4 v = *(const float4*)&h1s[wave][nb][i];
                a2[nb] += v.x * w[0] + v.y * w[1] + v.z * w[2] + v.w * w[3];
            }
        }
        // layer 3: 64 -> 1 (wave reduction)
        const float b2l = b2[lane];
        const float w3  = W3[lane];
        const float bb3 = b3[0];
        for (int nb = 0; nb < ebc; ++nb) {
            const float h2 = fmaxf(a2[nb] + b2l, 0.0f);
            float p = h2 * w3;
            p += __shfl_xor(p, 1);
            p += __shfl_xor(p, 2);
            p += __shfl_xor(p, 4);
            p += __shfl_xor(p, 8);
            p += __shfl_xor(p, 16);
            p += __shfl_xor(p, 32);
            if (lane == 0) out[base + nb] = p + bb3;
        }
    }
}

// ---------------------------------------------------------------------------
extern "C" void kernel_launch(void* const* d_in, const int* in_sizes, int n_in,
                              void* d_out, int out_size, void* d_ws, size_t ws_size,
                              hipStream_t stream) {
    const int*   type_idx   = (const int*)d_in[0];
    const int*   cat_idx    = (const int*)d_in[1];
    const int*   nbr_idx    = (const int*)d_in[2];
    const int*   nbr_mask   = (const int*)d_in[3];
    const int*   edges      = (const int*)d_in[4];
    const float* log_deg    = (const float*)d_in[5];
    const float* edge_feats = (const float*)d_in[6];
    const float* type_embed = (const float*)d_in[7];
    const float* cat0       = (const float*)d_in[8];
    const float* cat1       = (const float*)d_in[9];
    const float* deg_W      = (const float*)d_in[10];
    const float* deg_b      = (const float*)d_in[11];
    const float* proj_W     = (const float*)d_in[12];
    const float* proj_b     = (const float*)d_in[13];
    const float* attn_Wqkv  = (const float*)d_in[14];
    const float* attn_bqkv  = (const float*)d_in[15];
    const float* attn_Wo    = (const float*)d_in[16];
    const float* attn_bo    = (const float*)d_in[17];
    const float* eW1        = (const float*)d_in[18];
    const float* eb1        = (const float*)d_in[19];
    const float* eW2        = (const float*)d_in[20];
    const float* eb2        = (const float*)d_in[21];
    const float* eW3        = (const float*)d_in[22];
    const float* eb3        = (const float*)d_in[23];

    const int n  = in_sizes[0];        // N nodes
    const int ne = in_sizes[4] / 2;    // E edges
    float* out = (float*)d_out;

    // workspace layout: x0 | x1 | qkv   (needs n*640*4 bytes = 128 MB @ N=50k)
    float* x0   = (float*)d_ws;
    float* x1   = x0 + (size_t)n * HID;
    float* qkvb = x1 + (size_t)n * HID;

    encode_kernel<<<dim3(1024), dim3(128), 0, stream>>>(
        type_idx, cat_idx, log_deg, type_embed, cat0, cat1,
        deg_W, deg_b, proj_W, proj_b, x0, n);

    float* xc = x0;
    float* xn = x1;
    for (int l = 0; l < 3; ++l) {
        qkv_kernel<<<dim3(1024), dim3(128), 0, stream>>>(
            xc, attn_Wqkv + (size_t)l * 128 * 384, attn_bqkv + (size_t)l * 384,
            qkvb, n);
        attn_kernel<<<dim3(1024), dim3(256), 0, stream>>>(
            qkvb, xc, nbr_idx, nbr_mask,
            attn_Wo + (size_t)l * 128 * 128, attn_bo + (size_t)l * 128, xn, n);
        float* t = xc; xc = xn; xn = t;
    }

    edge_kernel<<<dim3(2048), dim3(256), 0, stream>>>(
        xc, edges, edge_feats, eW1, eb1, eW2, eb2, eW3, eb3, out, ne);
}

// Round 2
// 1091.164 us; speedup vs baseline: 1.3223x; 1.3223x over previous
//
#include <hip/hip_runtime.h>
#include <math.h>

#define HID 128

// bf16 helpers (RNE convert; values are finite so no NaN path needed)
static __device__ __forceinline__ unsigned short f2bf(float f) {
    unsigned u = __float_as_uint(f);
    u = (u + 0x7FFFu + ((u >> 16) & 1u)) >> 16;
    return (unsigned short)u;
}
static __device__ __forceinline__ float bf_lo(unsigned p) {   // element 0 (low 16 bits)
    return __uint_as_float(p << 16);
}
static __device__ __forceinline__ float bf_hi(unsigned p) {   // element 1 (high 16 bits)
    return __uint_as_float(p & 0xFFFF0000u);
}

// ---------------------------------------------------------------------------
// Kernel 1: node feature encode: feats(160) @ proj_W(160x128) + proj_b
// block = 128 threads (thread j = output dim j), 8 nodes per iteration
// ---------------------------------------------------------------------------
__global__ __launch_bounds__(128) void encode_kernel(
    const int* __restrict__ type_idx, const int* __restrict__ cat_idx,
    const float* __restrict__ log_deg,
    const float* __restrict__ type_embed, const float* __restrict__ cat0,
    const float* __restrict__ cat1, const float* __restrict__ deg_W,
    const float* __restrict__ deg_b, const float* __restrict__ proj_W,
    const float* __restrict__ proj_b, float* __restrict__ x, int n)
{
    __shared__ float feats[8][160];
    const int j = threadIdx.x;
    for (int base = blockIdx.x * 8; base < n; base += gridDim.x * 8) {
        const int nbc = min(8, n - base);
        for (int nb = 0; nb < nbc; ++nb) {
            const int node = base + nb;
            if (j < 64) {
                const int t = type_idx[node];
                feats[nb][j] = type_embed[t * 64 + j];
            } else if (j < 96) {
                const int c0 = cat_idx[node * 2 + 0];
                feats[nb][j] = cat0[c0 * 32 + (j - 64)];
            } else {
                const int c1 = cat_idx[node * 2 + 1];
                feats[nb][j] = cat1[c1 * 32 + (j - 96)];
            }
            if (j < 32) {
                const float ld = log_deg[node];
                feats[nb][128 + j] = fmaxf(ld * deg_W[j] + deg_b[j], 0.0f);
            }
        }
        __syncthreads();
        float acc[8];
        #pragma unroll
        for (int nb = 0; nb < 8; ++nb) acc[nb] = 0.0f;
        for (int i = 0; i < 160; i += 4) {
            float w[4];
            #pragma unroll
            for (int t = 0; t < 4; ++t) w[t] = proj_W[(i + t) * 128 + j];
            #pragma unroll
            for (int nb = 0; nb < 8; ++nb) {
                const float4 v = *(const float4*)&feats[nb][i];
                acc[nb] += v.x * w[0] + v.y * w[1] + v.z * w[2] + v.w * w[3];
            }
        }
        const float b = proj_b[j];
        for (int nb = 0; nb < nbc; ++nb)
            x[(size_t)(base + nb) * HID + j] = acc[nb] + b;
        __syncthreads();
    }
}

// ---------------------------------------------------------------------------
// Kernel 2: qkv projection, 16 nodes per block (exact grid = ceil(n/16)).
// q -> fp32 buffer [N][128]; k,v -> bf16 buffers [N][128] (L2-resident: 12.8MB each)
// ---------------------------------------------------------------------------
__global__ __launch_bounds__(128) void qkv_kernel(
    const float* __restrict__ x, const float* __restrict__ W,
    const float* __restrict__ b, float* __restrict__ qb,
    unsigned short* __restrict__ kb, unsigned short* __restrict__ vb, int n)
{
    __shared__ float xs[16][HID];
    const int j = threadIdx.x;
    const int base = blockIdx.x * 16;
    if (base >= n) return;
    const int nbc = min(16, n - base);
    for (int nb = 0; nb < nbc; ++nb)
        xs[nb][j] = x[(size_t)(base + nb) * HID + j];
    __syncthreads();
    float a0[16], a1[16], a2[16];
    #pragma unroll
    for (int nb = 0; nb < 16; ++nb) { a0[nb] = 0.f; a1[nb] = 0.f; a2[nb] = 0.f; }
    for (int i = 0; i < 128; i += 4) {
        float w0[4], w1[4], w2[4];
        #pragma unroll
        for (int t = 0; t < 4; ++t) {
            w0[t] = W[(i + t) * 384 + j];
            w1[t] = W[(i + t) * 384 + 128 + j];
            w2[t] = W[(i + t) * 384 + 256 + j];
        }
        #pragma unroll
        for (int nb = 0; nb < 16; ++nb) {
            const float4 v = *(const float4*)&xs[nb][i];
            a0[nb] += v.x * w0[0] + v.y * w0[1] + v.z * w0[2] + v.w * w0[3];
            a1[nb] += v.x * w1[0] + v.y * w1[1] + v.z * w1[2] + v.w * w1[3];
            a2[nb] += v.x * w2[0] + v.y * w2[1] + v.z * w2[2] + v.w * w2[3];
        }
    }
    const float bb0 = b[j], bb1 = b[128 + j], bb2 = b[256 + j];
    for (int nb = 0; nb < nbc; ++nb) {
        const size_t o = (size_t)(base + nb) * HID + j;
        qb[o] = a0[nb] + bb0;
        kb[o] = f2bf(a1[nb] + bb1);
        vb[o] = f2bf(a2[nb] + bb2);
    }
}

// ---------------------------------------------------------------------------
// Kernel 3: local attention (C = self + 16 nbrs) + output projection + relu.
// block = 256 (4 waves); wave per node-group of 4; exact grid (no loop).
// lane = head*16 + sub; lane covers dims (2*lane, 2*lane+1) of q/k/v layout.
// k/v are bf16 -> 256B gathers per context per wave, L2-resident.
// ---------------------------------------------------------------------------
__global__ __launch_bounds__(256) void attn_kernel(
    const float* __restrict__ qb, const unsigned short* __restrict__ kb,
    const unsigned short* __restrict__ vb, const float* __restrict__ x_in,
    const int* __restrict__ nbr_idx, const int* __restrict__ nbr_mask,
    const float* __restrict__ Wo, const float* __restrict__ bo,
    float* __restrict__ x_out, int n)
{
    __shared__ float o_s[4][4][HID];
    const int wave = threadIdx.x >> 6;
    const int lane = threadIdx.x & 63;
    const float scale = 0.17677669529663687f;   // 1/sqrt(32)
    const int base = (blockIdx.x * 4 + wave) * 4;
    if (base >= n) return;
    const int nbc = min(4, n - base);
    int hasn[4] = {0, 0, 0, 0};
    for (int nb = 0; nb < nbc; ++nb) {
        const int node = base + nb;
        const float2 q = *(const float2*)(qb + (size_t)node * HID + lane * 2);
        float s[17];
        int cix[17];
        int anyn = 0;
        #pragma unroll
        for (int c = 0; c < 17; ++c) {
            int cidx, valid;
            if (c == 0) { cidx = node; valid = 1; }
            else {
                cidx  = nbr_idx[node * 16 + (c - 1)];
                valid = nbr_mask[node * 16 + (c - 1)];
                anyn |= valid;
            }
            cix[c] = cidx;
            const unsigned kk = *(const unsigned*)(kb + (size_t)cidx * HID + lane * 2);
            float p = q.x * bf_lo(kk) + q.y * bf_hi(kk);
            p += __shfl_xor(p, 1);
            p += __shfl_xor(p, 2);
            p += __shfl_xor(p, 4);
            p += __shfl_xor(p, 8);
            s[c] = valid ? p * scale : -1e9f;
        }
        hasn[nb] = anyn;
        float mx = s[0];
        #pragma unroll
        for (int c = 1; c < 17; ++c) mx = fmaxf(mx, s[c]);
        float sum = 0.0f;
        #pragma unroll
        for (int c = 0; c < 17; ++c) { s[c] = __expf(s[c] - mx); sum += s[c]; }
        const float inv = 1.0f / sum;
        float ox = 0.0f, oy = 0.0f;
        #pragma unroll
        for (int c = 0; c < 17; ++c) {
            const unsigned vv = *(const unsigned*)(vb + (size_t)cix[c] * HID + lane * 2);
            const float a = s[c] * inv;
            ox += a * bf_lo(vv);
            oy += a * bf_hi(vv);
        }
        *(float2*)&o_s[wave][nb][lane * 2] = make_float2(ox, oy);
    }
    // same-wave producer/consumer on o_s: no __syncthreads needed
    float acc0[4] = {0.f, 0.f, 0.f, 0.f};
    float acc1[4] = {0.f, 0.f, 0.f, 0.f};
    for (int i = 0; i < 128; i += 4) {
        float w0[4], w1[4];
        #pragma unroll
        for (int t = 0; t < 4; ++t) {
            w0[t] = Wo[(i + t) * HID + lane];
            w1[t] = Wo[(i + t) * HID + 64 + lane];
        }
        #pragma unroll
        for (int nb = 0; nb < 4; ++nb) {
            const float4 v = *(const float4*)&o_s[wave][nb][i];
            acc0[nb] += v.x * w0[0] + v.y * w0[1] + v.z * w0[2] + v.w * w0[3];
            acc1[nb] += v.x * w1[0] + v.y * w1[1] + v.z * w1[2] + v.w * w1[3];
        }
    }
    const float b0 = bo[lane], b1 = bo[64 + lane];
    for (int nb = 0; nb < nbc; ++nb) {
        const int node = base + nb;
        float r0 = acc0[nb] + b0;
        float r1 = acc1[nb] + b1;
        if (!hasn[nb]) {             // wave-uniform branch
            r0 = x_in[(size_t)node * HID + lane];
            r1 = x_in[(size_t)node * HID + 64 + lane];
        }
        x_out[(size_t)node * HID + lane]      = fmaxf(r0, 0.0f);
        x_out[(size_t)node * HID + 64 + lane] = fmaxf(r1, 0.0f);
    }
}

// ---------------------------------------------------------------------------
// Kernel 4: edge MLP  concat(x[e0], x[e1], ef) (258) ->128 relu ->64 relu ->1
// block = 256 (4 waves); wave per edge-group of 16 (halves W1 L2 traffic).
// Layer1: lane computes out dims (lane, lane+64); h1 written in-place over in_s.
// ---------------------------------------------------------------------------
__global__ __launch_bounds__(256) void edge_kernel(
    const float* __restrict__ x, const int* __restrict__ edges,
    const float* __restrict__ edge_feats,
    const float* __restrict__ W1, const float* __restrict__ b1,
    const float* __restrict__ W2, const float* __restrict__ b2,
    const float* __restrict__ W3, const float* __restrict__ b3,
    float* __restrict__ out, int ne)
{
    __shared__ float in_s[4][16][260];   // 66.6 KB; reused in-place for h1
    const int wave = threadIdx.x >> 6;
    const int lane = threadIdx.x & 63;
    const int base = (blockIdx.x * 4 + wave) * 16;
    if (base >= ne) return;              // no __syncthreads in this kernel
    const int ebc = min(16, ne - base);
    for (int nb = 0; nb < ebc; ++nb) {
        const int e  = base + nb;
        const int e0 = edges[e * 2 + 0];
        const int e1 = edges[e * 2 + 1];
        *(float2*)&in_s[wave][nb][lane * 2] =
            *(const float2*)(x + (size_t)e0 * HID + lane * 2);
        *(float2*)&in_s[wave][nb][128 + lane * 2] =
            *(const float2*)(x + (size_t)e1 * HID + lane * 2);
        if (lane == 0) {
            in_s[wave][nb][256] = edge_feats[(size_t)e * 2 + 0];
            in_s[wave][nb][257] = edge_feats[(size_t)e * 2 + 1];
        }
    }
    // layer 1: 258 -> 128
    float a0[16], a1[16];
    #pragma unroll
    for (int nb = 0; nb < 16; ++nb) { a0[nb] = 0.f; a1[nb] = 0.f; }
    for (int i = 0; i < 256; i += 4) {
        float w0[4], w1[4];
        #pragma unroll
        for (int t = 0; t < 4; ++t) {
            w0[t] = W1[(i + t) * 128 + lane];
            w1[t] = W1[(i + t) * 128 + 64 + lane];
        }
        #pragma unroll
        for (int nb = 0; nb < 16; ++nb) {
            const float4 v = *(const float4*)&in_s[wave][nb][i];
            a0[nb] += v.x * w0[0] + v.y * w0[1] + v.z * w0[2] + v.w * w0[3];
            a1[nb] += v.x * w1[0] + v.y * w1[1] + v.z * w1[2] + v.w * w1[3];
        }
    }
    {   // i = 256, 257 (edge feats)
        const float w0a = W1[256 * 128 + lane], w1a = W1[256 * 128 + 64 + lane];
        const float w0b = W1[257 * 128 + lane], w1b = W1[257 * 128 + 64 + lane];
        #pragma unroll
        for (int nb = 0; nb < 16; ++nb) {
            const float2 v = *(const float2*)&in_s[wave][nb][256];
            a0[nb] += v.x * w0a + v.y * w0b;
            a1[nb] += v.x * w1a + v.y * w1b;
        }
    }
    // h1 = relu(a + b1), written in-place over in_s[wave][nb][0..127]
    // (all layer-1 reads of in_s are complete; same-wave LDS ordering)
    const float bb1_0 = b1[lane], bb1_1 = b1[64 + lane];
    for (int nb = 0; nb < ebc; ++nb) {
        in_s[wave][nb][lane]      = fmaxf(a0[nb] + bb1_0, 0.0f);
        in_s[wave][nb][64 + lane] = fmaxf(a1[nb] + bb1_1, 0.0f);
    }
    // layer 2: 128 -> 64 (lane = out dim)
    float a2[16];
    #pragma unroll
    for (int nb = 0; nb < 16; ++nb) a2[nb] = 0.f;
    for (int i = 0; i < 128; i += 4) {
        float w[4];
        #pragma unroll
        for (int t = 0; t < 4; ++t) w[t] = W2[(i + t) * 64 + lane];
        #pragma unroll
        for (int nb = 0; nb < 16; ++nb) {
            const float4 v = *(const float4*)&in_s[wave][nb][i];
            a2[nb] += v.x * w[0] + v.y * w[1] + v.z * w[2] + v.w * w[3];
        }
    }
    // layer 3: 64 -> 1 (wave reduction)
    const float b2l = b2[lane];
    const float w3  = W3[lane];
    const float bb3 = b3[0];
    for (int nb = 0; nb < ebc; ++nb) {
        const float h2 = fmaxf(a2[nb] + b2l, 0.0f);
        float p = h2 * w3;
        p += __shfl_xor(p, 1);
        p += __shfl_xor(p, 2);
        p += __shfl_xor(p, 4);
        p += __shfl_xor(p, 8);
        p += __shfl_xor(p, 16);
        p += __shfl_xor(p, 32);
        if (lane == 0) out[base + nb] = p + bb3;
    }
}

// ---------------------------------------------------------------------------
extern "C" void kernel_launch(void* const* d_in, const int* in_sizes, int n_in,
                              void* d_out, int out_size, void* d_ws, size_t ws_size,
                              hipStream_t stream) {
    const int*   type_idx   = (const int*)d_in[0];
    const int*   cat_idx    = (const int*)d_in[1];
    const int*   nbr_idx    = (const int*)d_in[2];
    const int*   nbr_mask   = (const int*)d_in[3];
    const int*   edges      = (const int*)d_in[4];
    const float* log_deg    = (const float*)d_in[5];
    const float* edge_feats = (const float*)d_in[6];
    const float* type_embed = (const float*)d_in[7];
    const float* cat0       = (const float*)d_in[8];
    const float* cat1       = (const float*)d_in[9];
    const float* deg_W      = (const float*)d_in[10];
    const float* deg_b      = (const float*)d_in[11];
    const float* proj_W     = (const float*)d_in[12];
    const float* proj_b     = (const float*)d_in[13];
    const float* attn_Wqkv  = (const float*)d_in[14];
    const float* attn_bqkv  = (const float*)d_in[15];
    const float* attn_Wo    = (const float*)d_in[16];
    const float* attn_bo    = (const float*)d_in[17];
    const float* eW1        = (const float*)d_in[18];
    const float* eb1        = (const float*)d_in[19];
    const float* eW2        = (const float*)d_in[20];
    const float* eb2        = (const float*)d_in[21];
    const float* eW3        = (const float*)d_in[22];
    const float* eb3        = (const float*)d_in[23];

    const int n  = in_sizes[0];        // N nodes
    const int ne = in_sizes[4] / 2;    // E edges
    float* out = (float*)d_out;

    // workspace layout: x0 | x1 | qb (fp32) | kb | vb (bf16)  -> ~102 MB
    float* x0 = (float*)d_ws;
    float* x1 = x0 + (size_t)n * HID;
    float* qb = x1 + (size_t)n * HID;
    unsigned short* kb = (unsigned short*)(qb + (size_t)n * HID);
    unsigned short* vb = kb + (size_t)n * HID;

    encode_kernel<<<dim3(1024), dim3(128), 0, stream>>>(
        type_idx, cat_idx, log_deg, type_embed, cat0, cat1,
        deg_W, deg_b, proj_W, proj_b, x0, n);

    const int qkv_grid  = (n + 15) / 16;
    const int attn_grid = (n + 15) / 16;    // 4 waves x 4 nodes per block
    float* xc = x0;
    float* xn = x1;
    for (int l = 0; l < 3; ++l) {
        qkv_kernel<<<dim3(qkv_grid), dim3(128), 0, stream>>>(
            xc, attn_Wqkv + (size_t)l * 128 * 384, attn_bqkv + (size_t)l * 384,
            qb, kb, vb, n);
        attn_kernel<<<dim3(attn_grid), dim3(256), 0, stream>>>(
            qb, kb, vb, xc, nbr_idx, nbr_mask,
            attn_Wo + (size_t)l * 128 * 128, attn_bo + (size_t)l * 128, xn, n);
        float* t = xc; xc = xn; xn = t;
    }

    const int edge_grid = (ne + 63) / 64;   // 4 waves x 16 edges per block
    edge_kernel<<<dim3(edge_grid), dim3(256), 0, stream>>>(
        xc, edges, edge_feats, eW1, eb1, eW2, eb2, eW3, eb3, out, ne);
}

// Round 3
// 786.400 us; speedup vs baseline: 1.8348x; 1.3875x over previous
//
#include <hip/hip_runtime.h>
#include <math.h>

#define HID 128

typedef short bf16x8 __attribute__((ext_vector_type(8)));
typedef float f32x4  __attribute__((ext_vector_type(4)));

// bf16 helpers (RNE convert; values are finite so no NaN path needed)
static __device__ __forceinline__ unsigned short f2bf(float f) {
    unsigned u = __float_as_uint(f);
    u = (u + 0x7FFFu + ((u >> 16) & 1u)) >> 16;
    return (unsigned short)u;
}
static __device__ __forceinline__ float bf_lo(unsigned p) {   // element 0 (low 16 bits)
    return __uint_as_float(p << 16);
}
static __device__ __forceinline__ float bf_hi(unsigned p) {   // element 1 (high 16 bits)
    return __uint_as_float(p & 0xFFFF0000u);
}

// ---------------------------------------------------------------------------
// Kernel 0: pack edge-MLP weights into MFMA B-fragment order (bf16).
// w1p: [8 nt][8 kk][64 lane][8 j]  <- W1[k=kk*32+(lane>>4)*8+j][n=nt*16+(lane&15)]
// w2p: [4 nt][4 kk][64 lane][8 j]  <- W2[k][n] likewise (k<128, n<64)
// ---------------------------------------------------------------------------
__global__ __launch_bounds__(256) void prep_kernel(
    const float* __restrict__ W1, const float* __restrict__ W2,
    unsigned short* __restrict__ w1p, unsigned short* __restrict__ w2p)
{
    const int idx = blockIdx.x * 256 + threadIdx.x;
    if (idx < 32768) {
        const int j = idx & 7, ln = (idx >> 3) & 63, kk = (idx >> 9) & 7, nt = idx >> 12;
        const int k = kk * 32 + (ln >> 4) * 8 + j;
        const int n = nt * 16 + (ln & 15);
        w1p[idx] = f2bf(W1[k * 128 + n]);
    } else if (idx < 32768 + 8192) {
        const int t = idx - 32768;
        const int j = t & 7, ln = (t >> 3) & 63, kk = (t >> 9) & 3, nt = t >> 11;
        const int k = kk * 32 + (ln >> 4) * 8 + j;
        const int n = nt * 16 + (ln & 15);
        w2p[t] = f2bf(W2[k * 64 + n]);
    }
}

// ---------------------------------------------------------------------------
// Kernel 1: node feature encode: feats(160) @ proj_W(160x128) + proj_b
// ---------------------------------------------------------------------------
__global__ __launch_bounds__(128) void encode_kernel(
    const int* __restrict__ type_idx, const int* __restrict__ cat_idx,
    const float* __restrict__ log_deg,
    const float* __restrict__ type_embed, const float* __restrict__ cat0,
    const float* __restrict__ cat1, const float* __restrict__ deg_W,
    const float* __restrict__ deg_b, const float* __restrict__ proj_W,
    const float* __restrict__ proj_b, float* __restrict__ x, int n)
{
    __shared__ float feats[8][160];
    const int j = threadIdx.x;
    for (int base = blockIdx.x * 8; base < n; base += gridDim.x * 8) {
        const int nbc = min(8, n - base);
        for (int nb = 0; nb < nbc; ++nb) {
            const int node = base + nb;
            if (j < 64) {
                const int t = type_idx[node];
                feats[nb][j] = type_embed[t * 64 + j];
            } else if (j < 96) {
                const int c0 = cat_idx[node * 2 + 0];
                feats[nb][j] = cat0[c0 * 32 + (j - 64)];
            } else {
                const int c1 = cat_idx[node * 2 + 1];
                feats[nb][j] = cat1[c1 * 32 + (j - 96)];
            }
            if (j < 32) {
                const float ld = log_deg[node];
                feats[nb][128 + j] = fmaxf(ld * deg_W[j] + deg_b[j], 0.0f);
            }
        }
        __syncthreads();
        float acc[8];
        #pragma unroll
        for (int nb = 0; nb < 8; ++nb) acc[nb] = 0.0f;
        for (int i = 0; i < 160; i += 4) {
            float w[4];
            #pragma unroll
            for (int t = 0; t < 4; ++t) w[t] = proj_W[(i + t) * 128 + j];
            #pragma unroll
            for (int nb = 0; nb < 8; ++nb) {
                const float4 v = *(const float4*)&feats[nb][i];
                acc[nb] += v.x * w[0] + v.y * w[1] + v.z * w[2] + v.w * w[3];
            }
        }
        const float b = proj_b[j];
        for (int nb = 0; nb < nbc; ++nb)
            x[(size_t)(base + nb) * HID + j] = acc[nb] + b;
        __syncthreads();
    }
}

// ---------------------------------------------------------------------------
// Kernel 2: qkv projection, 16 nodes per block.
// q -> fp32; k,v -> bf16 (L2-resident gathers for attn).
// ---------------------------------------------------------------------------
__global__ __launch_bounds__(128) void qkv_kernel(
    const float* __restrict__ x, const float* __restrict__ W,
    const float* __restrict__ b, float* __restrict__ qb,
    unsigned short* __restrict__ kb, unsigned short* __restrict__ vb, int n)
{
    __shared__ float xs[16][HID];
    const int j = threadIdx.x;
    const int base = blockIdx.x * 16;
    if (base >= n) return;
    const int nbc = min(16, n - base);
    for (int nb = 0; nb < nbc; ++nb)
        xs[nb][j] = x[(size_t)(base + nb) * HID + j];
    __syncthreads();
    float a0[16], a1[16], a2[16];
    #pragma unroll
    for (int nb = 0; nb < 16; ++nb) { a0[nb] = 0.f; a1[nb] = 0.f; a2[nb] = 0.f; }
    for (int i = 0; i < 128; i += 4) {
        float w0[4], w1[4], w2[4];
        #pragma unroll
        for (int t = 0; t < 4; ++t) {
            w0[t] = W[(i + t) * 384 + j];
            w1[t] = W[(i + t) * 384 + 128 + j];
            w2[t] = W[(i + t) * 384 + 256 + j];
        }
        #pragma unroll
        for (int nb = 0; nb < 16; ++nb) {
            const float4 v = *(const float4*)&xs[nb][i];
            a0[nb] += v.x * w0[0] + v.y * w0[1] + v.z * w0[2] + v.w * w0[3];
            a1[nb] += v.x * w1[0] + v.y * w1[1] + v.z * w1[2] + v.w * w1[3];
            a2[nb] += v.x * w2[0] + v.y * w2[1] + v.z * w2[2] + v.w * w2[3];
        }
    }
    const float bb0 = b[j], bb1 = b[128 + j], bb2 = b[256 + j];
    for (int nb = 0; nb < nbc; ++nb) {
        const size_t o = (size_t)(base + nb) * HID + j;
        qb[o] = a0[nb] + bb0;
        kb[o] = f2bf(a1[nb] + bb1);
        vb[o] = f2bf(a2[nb] + bb2);
    }
}

// ---------------------------------------------------------------------------
// Kernel 3: local attention (C = self + 16 nbrs) + output projection + relu.
// block = 256 (4 waves); wave per node-group of 4; exact grid.
// If xb_out != null (last layer) writes bf16 x for the edge MLP instead of fp32.
// ---------------------------------------------------------------------------
__global__ __launch_bounds__(256) void attn_kernel(
    const float* __restrict__ qb, const unsigned short* __restrict__ kb,
    const unsigned short* __restrict__ vb, const float* __restrict__ x_in,
    const int* __restrict__ nbr_idx, const int* __restrict__ nbr_mask,
    const float* __restrict__ Wo, const float* __restrict__ bo,
    float* __restrict__ x_out, unsigned short* __restrict__ xb_out, int n)
{
    __shared__ float o_s[4][4][HID];
    const int wave = threadIdx.x >> 6;
    const int lane = threadIdx.x & 63;
    const float scale = 0.17677669529663687f;   // 1/sqrt(32)
    const int base = (blockIdx.x * 4 + wave) * 4;
    if (base >= n) return;
    const int nbc = min(4, n - base);
    int hasn[4] = {0, 0, 0, 0};
    for (int nb = 0; nb < nbc; ++nb) {
        const int node = base + nb;
        const float2 q = *(const float2*)(qb + (size_t)node * HID + lane * 2);
        float s[17];
        int cix[17];
        int anyn = 0;
        #pragma unroll
        for (int c = 0; c < 17; ++c) {
            int cidx, valid;
            if (c == 0) { cidx = node; valid = 1; }
            else {
                cidx  = nbr_idx[node * 16 + (c - 1)];
                valid = nbr_mask[node * 16 + (c - 1)];
                anyn |= valid;
            }
            cix[c] = cidx;
            const unsigned kk = *(const unsigned*)(kb + (size_t)cidx * HID + lane * 2);
            float p = q.x * bf_lo(kk) + q.y * bf_hi(kk);
            p += __shfl_xor(p, 1);
            p += __shfl_xor(p, 2);
            p += __shfl_xor(p, 4);
            p += __shfl_xor(p, 8);
            s[c] = valid ? p * scale : -1e9f;
        }
        hasn[nb] = anyn;
        float mx = s[0];
        #pragma unroll
        for (int c = 1; c < 17; ++c) mx = fmaxf(mx, s[c]);
        float sum = 0.0f;
        #pragma unroll
        for (int c = 0; c < 17; ++c) { s[c] = __expf(s[c] - mx); sum += s[c]; }
        const float inv = 1.0f / sum;
        float ox = 0.0f, oy = 0.0f;
        #pragma unroll
        for (int c = 0; c < 17; ++c) {
            const unsigned vv = *(const unsigned*)(vb + (size_t)cix[c] * HID + lane * 2);
            const float a = s[c] * inv;
            ox += a * bf_lo(vv);
            oy += a * bf_hi(vv);
        }
        *(float2*)&o_s[wave][nb][lane * 2] = make_float2(ox, oy);
    }
    // same-wave producer/consumer on o_s: no __syncthreads needed
    float acc0[4] = {0.f, 0.f, 0.f, 0.f};
    float acc1[4] = {0.f, 0.f, 0.f, 0.f};
    for (int i = 0; i < 128; i += 4) {
        float w0[4], w1[4];
        #pragma unroll
        for (int t = 0; t < 4; ++t) {
            w0[t] = Wo[(i + t) * HID + lane];
            w1[t] = Wo[(i + t) * HID + 64 + lane];
        }
        #pragma unroll
        for (int nb = 0; nb < 4; ++nb) {
            const float4 v = *(const float4*)&o_s[wave][nb][i];
            acc0[nb] += v.x * w0[0] + v.y * w0[1] + v.z * w0[2] + v.w * w0[3];
            acc1[nb] += v.x * w1[0] + v.y * w1[1] + v.z * w1[2] + v.w * w1[3];
        }
    }
    const float b0 = bo[lane], b1 = bo[64 + lane];
    for (int nb = 0; nb < nbc; ++nb) {
        const int node = base + nb;
        float r0 = acc0[nb] + b0;
        float r1 = acc1[nb] + b1;
        if (!hasn[nb]) {             // wave-uniform branch
            r0 = x_in[(size_t)node * HID + lane];
            r1 = x_in[(size_t)node * HID + 64 + lane];
        }
        if (xb_out) {
            xb_out[(size_t)node * HID + lane]      = f2bf(fmaxf(r0, 0.0f));
            xb_out[(size_t)node * HID + 64 + lane] = f2bf(fmaxf(r1, 0.0f));
        } else {
            x_out[(size_t)node * HID + lane]      = fmaxf(r0, 0.0f);
            x_out[(size_t)node * HID + 64 + lane] = fmaxf(r1, 0.0f);
        }
    }
}

// ---------------------------------------------------------------------------
// Kernel 4: edge MLP via MFMA.  Wave = 16 edges x full 128->64->1 pipeline.
// A-frags gathered directly from global bf16 x rows (no LDS staging).
// h1 round-trips through a 4KB/wave XOR-swizzled LDS tile (byte ^= row<<4)
// to convert MFMA C/D layout -> next A layout without bank conflicts.
// ---------------------------------------------------------------------------
__global__ __launch_bounds__(256) void edge_mfma_kernel(
    const unsigned short* __restrict__ xb,    // [N][128] bf16
    const int* __restrict__ edges,
    const float* __restrict__ edge_feats,
    const unsigned short* __restrict__ w1p,   // packed B-frags, 32768
    const unsigned short* __restrict__ w2p,   // packed B-frags, 8192
    const float* __restrict__ W1,             // fp32 (rows 256,257 used)
    const float* __restrict__ b1,
    const float* __restrict__ b2,
    const float* __restrict__ W3, const float* __restrict__ b3,
    float* __restrict__ out, int ne)
{
    __shared__ __align__(16) unsigned short h1s[4][16 * 128];  // swizzled bf16
    const int wave = threadIdx.x >> 6;
    const int lane = threadIdx.x & 63;
    const int g    = lane >> 4;     // k-group (A/B) / row-group (C/D)
    const int c    = lane & 15;     // A row / B,D col
    const int base = (blockIdx.x * 4 + wave) * 16;
    if (base >= ne) return;

    // node indices for A row = c
    const int erow = min(base + c, ne - 1);
    const int e0 = edges[erow * 2 + 0];
    const int e1 = edges[erow * 2 + 1];

    // ---- layer 1: [16,256] x [256,128] via 8nt x 8kk MFMAs
    f32x4 C1[8];
    #pragma unroll
    for (int nt = 0; nt < 8; ++nt) C1[nt] = (f32x4){0.f, 0.f, 0.f, 0.f};
    #pragma unroll
    for (int kk = 0; kk < 8; ++kk) {
        const int node = (kk < 4) ? e0 : e1;
        const bf16x8 a = *(const bf16x8*)(xb + (size_t)node * 128 + (kk & 3) * 32 + g * 8);
        #pragma unroll
        for (int nt = 0; nt < 8; ++nt) {
            const bf16x8 bf = *(const bf16x8*)(w1p + ((nt * 8 + kk) * 64 + lane) * 8);
            C1[nt] = __builtin_amdgcn_mfma_f32_16x16x32_bf16(a, bf, C1[nt], 0, 0, 0);
        }
    }

    // ---- epilogue 1: + b1 + ef @ W1[256:258] ; relu ; bf16 -> swizzled LDS
    float ef0[4], ef1[4];
    #pragma unroll
    for (int r = 0; r < 4; ++r) {
        const int m = min(base + g * 4 + r, ne - 1);
        ef0[r] = edge_feats[(size_t)m * 2 + 0];
        ef1[r] = edge_feats[(size_t)m * 2 + 1];
    }
    char* const h1base = (char*)&h1s[wave][0];
    #pragma unroll
    for (int nt = 0; nt < 8; ++nt) {
        const int n   = nt * 16 + c;
        const float bb  = b1[n];
        const float wc0 = W1[256 * 128 + n];
        const float wc1 = W1[257 * 128 + n];
        #pragma unroll
        for (int r = 0; r < 4; ++r) {
            const int rr = g * 4 + r;
            const float h = fmaxf(C1[nt][r] + bb + ef0[r] * wc0 + ef1[r] * wc1, 0.0f);
            *(unsigned short*)(h1base + rr * 256 + ((n * 2) ^ (rr << 4))) = f2bf(h);
        }
    }

    // ---- layer 2: [16,128] x [128,64] via 4nt x 4kk MFMAs
    f32x4 C2[4];
    #pragma unroll
    for (int nt = 0; nt < 4; ++nt) C2[nt] = (f32x4){0.f, 0.f, 0.f, 0.f};
    #pragma unroll
    for (int kk = 0; kk < 4; ++kk) {
        const int k0b = kk * 64 + g * 16;              // byte offset of k-chunk
        const bf16x8 a = *(const bf16x8*)(h1base + c * 256 + (k0b ^ (c << 4)));
        #pragma unroll
        for (int nt = 0; nt < 4; ++nt) {
            const bf16x8 bf = *(const bf16x8*)(w2p + ((nt * 4 + kk) * 64 + lane) * 8);
            C2[nt] = __builtin_amdgcn_mfma_f32_16x16x32_bf16(a, bf, C2[nt], 0, 0, 0);
        }
    }

    // ---- layer 3: relu(h2) @ W3 + b3, 16-lane tree reduce
    const float bb3 = b3[0];
    #pragma unroll
    for (int r = 0; r < 4; ++r) {
        float acc = 0.0f;
        #pragma unroll
        for (int nt = 0; nt < 4; ++nt) {
            const int n2 = nt * 16 + c;
            acc += fmaxf(C2[nt][r] + b2[n2], 0.0f) * W3[n2];
        }
        acc += __shfl_xor(acc, 1);
        acc += __shfl_xor(acc, 2);
        acc += __shfl_xor(acc, 4);
        acc += __shfl_xor(acc, 8);
        const int m = base + g * 4 + r;
        if (c == 0 && m < ne) out[m] = acc + bb3;
    }
}

// ---------------------------------------------------------------------------
extern "C" void kernel_launch(void* const* d_in, const int* in_sizes, int n_in,
                              void* d_out, int out_size, void* d_ws, size_t ws_size,
                              hipStream_t stream) {
    const int*   type_idx   = (const int*)d_in[0];
    const int*   cat_idx    = (const int*)d_in[1];
    const int*   nbr_idx    = (const int*)d_in[2];
    const int*   nbr_mask   = (const int*)d_in[3];
    const int*   edges      = (const int*)d_in[4];
    const float* log_deg    = (const float*)d_in[5];
    const float* edge_feats = (const float*)d_in[6];
    const float* type_embed = (const float*)d_in[7];
    const float* cat0       = (const float*)d_in[8];
    const float* cat1       = (const float*)d_in[9];
    const float* deg_W      = (const float*)d_in[10];
    const float* deg_b      = (const float*)d_in[11];
    const float* proj_W     = (const float*)d_in[12];
    const float* proj_b     = (const float*)d_in[13];
    const float* attn_Wqkv  = (const float*)d_in[14];
    const float* attn_bqkv  = (const float*)d_in[15];
    const float* attn_Wo    = (const float*)d_in[16];
    const float* attn_bo    = (const float*)d_in[17];
    const float* eW1        = (const float*)d_in[18];
    const float* eb1        = (const float*)d_in[19];
    const float* eW2        = (const float*)d_in[20];
    const float* eb2        = (const float*)d_in[21];
    const float* eW3        = (const float*)d_in[22];
    const float* eb3        = (const float*)d_in[23];

    const int n  = in_sizes[0];        // N nodes
    const int ne = in_sizes[4] / 2;    // E edges
    float* out = (float*)d_out;

    // workspace: x0 | x1 | qb (fp32 N*128 each) | kb | vb (bf16) | w1p | w2p
    // xb (bf16 final x) aliases x1 (free after layer 1->0->xb chain).
    float* x0 = (float*)d_ws;
    float* x1 = x0 + (size_t)n * HID;
    float* qb = x1 + (size_t)n * HID;
    unsigned short* kb  = (unsigned short*)(qb + (size_t)n * HID);
    unsigned short* vb  = kb + (size_t)n * HID;
    unsigned short* w1p = vb + (size_t)n * HID;
    unsigned short* w2p = w1p + 32768;
    unsigned short* xb  = (unsigned short*)x1;   // alias: safe, see layer loop

    prep_kernel<<<dim3(160), dim3(256), 0, stream>>>(eW1, eW2, w1p, w2p);

    encode_kernel<<<dim3(1024), dim3(128), 0, stream>>>(
        type_idx, cat_idx, log_deg, type_embed, cat0, cat1,
        deg_W, deg_b, proj_W, proj_b, x0, n);

    const int qkv_grid  = (n + 15) / 16;
    const int attn_grid = (n + 15) / 16;    // 4 waves x 4 nodes per block
    // l=0: x0 -> x1 ; l=1: x1 -> x0 ; l=2: x0 -> xb (bf16, aliases x1)
    float* xc = x0;
    float* xn = x1;
    for (int l = 0; l < 3; ++l) {
        qkv_kernel<<<dim3(qkv_grid), dim3(128), 0, stream>>>(
            xc, attn_Wqkv + (size_t)l * 128 * 384, attn_bqkv + (size_t)l * 384,
            qb, kb, vb, n);
        attn_kernel<<<dim3(attn_grid), dim3(256), 0, stream>>>(
            qb, kb, vb, xc, nbr_idx, nbr_mask,
            attn_Wo + (size_t)l * 128 * 128, attn_bo + (size_t)l * 128,
            xn, (l == 2) ? xb : (unsigned short*)nullptr, n);
        float* t = xc; xc = xn; xn = t;
    }

    const int edge_grid = (ne + 63) / 64;   // 4 waves x 16 edges per block
    edge_mfma_kernel<<<dim3(edge_grid), dim3(256), 0, stream>>>(
        xb, edges, edge_feats, w1p, w2p, eW1, eb1, eb2, eW3, eb3, out, ne);
}

// Round 5
// 526.816 us; speedup vs baseline: 2.7388x; 1.4927x over previous
//
#include <hip/hip_runtime.h>
#include <math.h>

#define HID 128

typedef _Float16 f16x8 __attribute__((ext_vector_type(8)));
typedef float    f32x4 __attribute__((ext_vector_type(4)));

static __device__ __forceinline__ float h_lo(unsigned p) {
    return (float)__builtin_bit_cast(_Float16, (unsigned short)p);
}
static __device__ __forceinline__ float h_hi(unsigned p) {
    return (float)__builtin_bit_cast(_Float16, (unsigned short)(p >> 16));
}
static __device__ __forceinline__ unsigned pack2h(float x, float y) {
    const unsigned short lx = __builtin_bit_cast(unsigned short, (_Float16)x);
    const unsigned short ly = __builtin_bit_cast(unsigned short, (_Float16)y);
    return ((unsigned)ly << 16) | lx;
}

// ---------------------------------------------------------------------------
// Kernel 0: pack ALL GEMM weights into fp16 MFMA B-fragment order.
// B-frag layout: [NT][KK][64 lane][8 j]; elem = W[k = KK*32+(ln>>4)*8+j][n = NT*16+(ln&15)]
// regions: wqkvp 3x[24][4] | wop 3x[8][4] | w1p [8][8] | w2p [4][4]
// ---------------------------------------------------------------------------
__global__ __launch_bounds__(256) void prep_kernel(
    const float* __restrict__ Wqkv, const float* __restrict__ Wo,
    const float* __restrict__ W1, const float* __restrict__ W2,
    _Float16* __restrict__ dst)
{
    const int idx = blockIdx.x * 256 + threadIdx.x;
    if (idx < 147456) {                     // wqkvp: 3 layers x 24nt x 4kk
        const int l = idx / 49152, t = idx % 49152;
        const int j = t & 7, ln = (t >> 3) & 63, kk = (t >> 9) & 3, nt = t >> 11;
        const int k = kk * 32 + (ln >> 4) * 8 + j, n = nt * 16 + (ln & 15);
        dst[idx] = (_Float16)Wqkv[((size_t)l * 128 + k) * 384 + n];
    } else if (idx < 196608) {              // wop: 3 layers x 8nt x 4kk
        const int t0 = idx - 147456;
        const int l = t0 / 16384, t = t0 % 16384;
        const int j = t & 7, ln = (t >> 3) & 63, kk = (t >> 9) & 3, nt = t >> 11;
        const int k = kk * 32 + (ln >> 4) * 8 + j, n = nt * 16 + (ln & 15);
        dst[idx] = (_Float16)Wo[((size_t)l * 128 + k) * 128 + n];
    } else if (idx < 229376) {              // w1p: 8nt x 8kk (k<256)
        const int t = idx - 196608;
        const int j = t & 7, ln = (t >> 3) & 63, kk = (t >> 9) & 7, nt = t >> 12;
        const int k = kk * 32 + (ln >> 4) * 8 + j, n = nt * 16 + (ln & 15);
        dst[idx] = (_Float16)W1[k * 128 + n];
    } else if (idx < 237568) {              // w2p: 4nt x 4kk
        const int t = idx - 229376;
        const int j = t & 7, ln = (t >> 3) & 63, kk = (t >> 9) & 3, nt = t >> 11;
        const int k = kk * 32 + (ln >> 4) * 8 + j, n = nt * 16 + (ln & 15);
        dst[idx] = (_Float16)W2[k * 64 + n];
    }
}

// ---------------------------------------------------------------------------
// Kernel 1: node feature encode -> xh (fp16)
// ---------------------------------------------------------------------------
__global__ __launch_bounds__(128) void encode_kernel(
    const int* __restrict__ type_idx, const int* __restrict__ cat_idx,
    const float* __restrict__ log_deg,
    const float* __restrict__ type_embed, const float* __restrict__ cat0,
    const float* __restrict__ cat1, const float* __restrict__ deg_W,
    const float* __restrict__ deg_b, const float* __restrict__ proj_W,
    const float* __restrict__ proj_b, _Float16* __restrict__ xh, int n)
{
    __shared__ float feats[8][160];
    const int j = threadIdx.x;
    for (int base = blockIdx.x * 8; base < n; base += gridDim.x * 8) {
        const int nbc = min(8, n - base);
        for (int nb = 0; nb < nbc; ++nb) {
            const int node = base + nb;
            if (j < 64) {
                feats[nb][j] = type_embed[type_idx[node] * 64 + j];
            } else if (j < 96) {
                feats[nb][j] = cat0[cat_idx[node * 2 + 0] * 32 + (j - 64)];
            } else {
                feats[nb][j] = cat1[cat_idx[node * 2 + 1] * 32 + (j - 96)];
            }
            if (j < 32) {
                const float ld = log_deg[node];
                feats[nb][128 + j] = fmaxf(ld * deg_W[j] + deg_b[j], 0.0f);
            }
        }
        __syncthreads();
        float acc[8];
        #pragma unroll
        for (int nb = 0; nb < 8; ++nb) acc[nb] = 0.0f;
        for (int i = 0; i < 160; i += 4) {
            float w[4];
            #pragma unroll
            for (int t = 0; t < 4; ++t) w[t] = proj_W[(i + t) * 128 + j];
            #pragma unroll
            for (int nb = 0; nb < 8; ++nb) {
                const float4 v = *(const float4*)&feats[nb][i];
                acc[nb] += v.x * w[0] + v.y * w[1] + v.z * w[2] + v.w * w[3];
            }
        }
        const float b = proj_b[j];
        for (int nb = 0; nb < nbc; ++nb)
            xh[(size_t)(base + nb) * HID + j] = (_Float16)(acc[nb] + b);
        __syncthreads();
    }
}

// tile swizzle: byte addr = row*256 + ((col*2) ^ (row<<4)), rows 0..15, cols 0..127
// full-coverage coalesced tile->global write (FIX of round 4's half-width bug):
// 4 iters x 64 lanes = 256 (row, 16B-chunk) pairs = 16 rows x 16 chunks.
#define TILE_STORE(dst)                                                        \
    _Pragma("unroll")                                                          \
    for (int t = 0; t < 4; ++t) {                                              \
        const int lr  = t * 4 + (lane >> 4);                                   \
        const int j16 = lane & 15;                                             \
        const f16x8 v = *(const f16x8*)(tb + lr * 256 + ((j16 * 16) ^ (lr << 4))); \
        if (base + lr < n)                                                     \
            *(f16x8*)((dst) + (size_t)(base + lr) * 128 + j16 * 8) = v;        \
    }

// ---------------------------------------------------------------------------
// Kernel 2a: qkv from xh (layer 0).  Wave = 16 nodes; 3 parts (q,k,v) x 8nt x 4kk.
// ---------------------------------------------------------------------------
__global__ __launch_bounds__(256) void qkv0_kernel(
    const _Float16* __restrict__ xh, const _Float16* __restrict__ wq,
    const float* __restrict__ bqkv,
    _Float16* __restrict__ qh, _Float16* __restrict__ kh, _Float16* __restrict__ vh,
    int n)
{
    __shared__ __align__(16) _Float16 tile[4][16 * 128];
    const int wave = threadIdx.x >> 6;
    const int lane = threadIdx.x & 63;
    const int g = lane >> 4, c = lane & 15;
    const int base = (blockIdx.x * 4 + wave) * 16;
    if (base >= n) return;
    const int arow = min(base + c, n - 1);
    f16x8 a[4];
    #pragma unroll
    for (int kk = 0; kk < 4; ++kk)
        a[kk] = *(const f16x8*)(xh + (size_t)arow * 128 + kk * 32 + g * 8);
    char* const tb = (char*)&tile[wave][0];
    _Float16* outs[3] = {qh, kh, vh};
    #pragma unroll
    for (int part = 0; part < 3; ++part) {
        f32x4 C[8];
        #pragma unroll
        for (int nt = 0; nt < 8; ++nt) C[nt] = (f32x4){0.f, 0.f, 0.f, 0.f};
        #pragma unroll
        for (int kk = 0; kk < 4; ++kk) {
            #pragma unroll
            for (int nt = 0; nt < 8; ++nt) {
                const f16x8 bf = *(const f16x8*)(wq + (((part * 8 + nt) * 4 + kk) << 9) + lane * 8);
                C[nt] = __builtin_amdgcn_mfma_f32_16x16x32_f16(a[kk], bf, C[nt], 0, 0, 0);
            }
        }
        #pragma unroll
        for (int nt = 0; nt < 8; ++nt) {
            const int nn = nt * 16 + c;
            const float bb = bqkv[part * 128 + nn];
            #pragma unroll
            for (int r = 0; r < 4; ++r) {
                const int rr = g * 4 + r;
                *(_Float16*)(tb + rr * 256 + ((nn * 2) ^ (rr << 4))) = (_Float16)(C[nt][r] + bb);
            }
        }
        _Float16* const dst = outs[part];
        TILE_STORE(dst)
    }
}

// ---------------------------------------------------------------------------
// Kernel 2b: fused out-proj (+fallback+relu) and optional next-layer qkv.
// x_next = relu(mask ? o@Wo + bo : x_prev);  then qkv = x_next @ Wqkv_next.
// ---------------------------------------------------------------------------
__global__ __launch_bounds__(256) void projqkv_kernel(
    const _Float16* __restrict__ oh, const int* __restrict__ mask,
    const _Float16* __restrict__ xh_prev,
    const _Float16* __restrict__ wo, const float* __restrict__ bo,
    const _Float16* __restrict__ wq, const float* __restrict__ bqkv,
    _Float16* __restrict__ xh_next,
    _Float16* __restrict__ qh, _Float16* __restrict__ kh, _Float16* __restrict__ vh,
    int do_qkv, int n)
{
    __shared__ __align__(16) _Float16 tile[4][16 * 128];
    const int wave = threadIdx.x >> 6;
    const int lane = threadIdx.x & 63;
    const int g = lane >> 4, c = lane & 15;
    const int base = (blockIdx.x * 4 + wave) * 16;
    if (base >= n) return;
    const int arow = min(base + c, n - 1);
    char* const tb = (char*)&tile[wave][0];

    // ---- phase 1: o @ Wo
    f32x4 Cp[8];
    #pragma unroll
    for (int nt = 0; nt < 8; ++nt) Cp[nt] = (f32x4){0.f, 0.f, 0.f, 0.f};
    #pragma unroll
    for (int kk = 0; kk < 4; ++kk) {
        const f16x8 a = *(const f16x8*)(oh + (size_t)arow * 128 + kk * 32 + g * 8);
        #pragma unroll
        for (int nt = 0; nt < 8; ++nt) {
            const f16x8 bf = *(const f16x8*)(wo + ((nt * 4 + kk) << 9) + lane * 8);
            Cp[nt] = __builtin_amdgcn_mfma_f32_16x16x32_f16(a, bf, Cp[nt], 0, 0, 0);
        }
    }
    int mk[4]; int rrow[4];
    #pragma unroll
    for (int r = 0; r < 4; ++r) {
        rrow[r] = min(base + g * 4 + r, n - 1);
        mk[r] = mask[rrow[r]];
    }
    #pragma unroll
    for (int nt = 0; nt < 8; ++nt) {
        const int nn = nt * 16 + c;
        const float bb = bo[nn];
        #pragma unroll
        for (int r = 0; r < 4; ++r) {
            float val = Cp[nt][r] + bb;
            if (!mk[r]) val = (float)xh_prev[(size_t)rrow[r] * 128 + nn];
            val = fmaxf(val, 0.0f);
            const int rr = g * 4 + r;
            *(_Float16*)(tb + rr * 256 + ((nn * 2) ^ (rr << 4))) = (_Float16)val;
        }
    }
    // write x_next coalesced (full 128 cols)
    TILE_STORE(xh_next)
    if (!do_qkv) return;

    // ---- phase 2: x_next @ Wqkv (A-frags read from tile BEFORE overwriting it)
    f16x8 a2[4];
    #pragma unroll
    for (int kk = 0; kk < 4; ++kk)
        a2[kk] = *(const f16x8*)(tb + c * 256 + ((kk * 64 + g * 16) ^ (c << 4)));
    _Float16* outs[3] = {qh, kh, vh};
    #pragma unroll
    for (int part = 0; part < 3; ++part) {
        f32x4 C[8];
        #pragma unroll
        for (int nt = 0; nt < 8; ++nt) C[nt] = (f32x4){0.f, 0.f, 0.f, 0.f};
        #pragma unroll
        for (int kk = 0; kk < 4; ++kk) {
            #pragma unroll
            for (int nt = 0; nt < 8; ++nt) {
                const f16x8 bf = *(const f16x8*)(wq + (((part * 8 + nt) * 4 + kk) << 9) + lane * 8);
                C[nt] = __builtin_amdgcn_mfma_f32_16x16x32_f16(a2[kk], bf, C[nt], 0, 0, 0);
            }
        }
        #pragma unroll
        for (int nt = 0; nt < 8; ++nt) {
            const int nn = nt * 16 + c;
            const float bb = bqkv[part * 128 + nn];
            #pragma unroll
            for (int r = 0; r < 4; ++r) {
                const int rr = g * 4 + r;
                *(_Float16*)(tb + rr * 256 + ((nn * 2) ^ (rr << 4))) = (_Float16)(C[nt][r] + bb);
            }
        }
        _Float16* const dst = outs[part];
        TILE_STORE(dst)
    }
}

// ---------------------------------------------------------------------------
// Kernel 3: attention core: scores + softmax + PV.  Writes o (fp16) + mask.
// wave per node-group of 4; lane covers dims (2*lane, 2*lane+1).
// ---------------------------------------------------------------------------
__global__ __launch_bounds__(256) void attn_kernel(
    const _Float16* __restrict__ qh, const _Float16* __restrict__ kh,
    const _Float16* __restrict__ vh,
    const int* __restrict__ nbr_idx, const int* __restrict__ nbr_mask,
    _Float16* __restrict__ oh, int* __restrict__ mask_out, int n)
{
    const int wave = threadIdx.x >> 6;
    const int lane = threadIdx.x & 63;
    const float scale = 0.17677669529663687f;   // 1/sqrt(32)
    const int base = (blockIdx.x * 4 + wave) * 4;
    if (base >= n) return;
    const int nbc = min(4, n - base);
    for (int nb = 0; nb < nbc; ++nb) {
        const int node = base + nb;
        const unsigned qq = *(const unsigned*)(qh + (size_t)node * HID + lane * 2);
        const float qx = h_lo(qq), qy = h_hi(qq);
        float s[17];
        int cix[17];
        int anyn = 0;
        #pragma unroll
        for (int c = 0; c < 17; ++c) {
            int cidx, valid;
            if (c == 0) { cidx = node; valid = 1; }
            else {
                cidx  = nbr_idx[node * 16 + (c - 1)];
                valid = nbr_mask[node * 16 + (c - 1)];
                anyn |= valid;
            }
            cix[c] = cidx;
            const unsigned kk = *(const unsigned*)(kh + (size_t)cidx * HID + lane * 2);
            float p = qx * h_lo(kk) + qy * h_hi(kk);
            p += __shfl_xor(p, 1);
            p += __shfl_xor(p, 2);
            p += __shfl_xor(p, 4);
            p += __shfl_xor(p, 8);
            s[c] = valid ? p * scale : -1e9f;
        }
        if (lane == 0) mask_out[node] = anyn;
        float mx = s[0];
        #pragma unroll
        for (int c = 1; c < 17; ++c) mx = fmaxf(mx, s[c]);
        float sum = 0.0f;
        #pragma unroll
        for (int c = 0; c < 17; ++c) { s[c] = __expf(s[c] - mx); sum += s[c]; }
        const float inv = 1.0f / sum;
        float ox = 0.0f, oy = 0.0f;
        #pragma unroll
        for (int c = 0; c < 17; ++c) {
            const unsigned vv = *(const unsigned*)(vh + (size_t)cix[c] * HID + lane * 2);
            const float a = s[c] * inv;
            ox += a * h_lo(vv);
            oy += a * h_hi(vv);
        }
        *(unsigned*)(oh + (size_t)node * HID + lane * 2) = pack2h(ox, oy);
    }
}

// ---------------------------------------------------------------------------
// Kernel 4: edge MLP via fp16 MFMA (structure proven in round 3).
// ---------------------------------------------------------------------------
__global__ __launch_bounds__(256) void edge_mfma_kernel(
    const _Float16* __restrict__ xh,          // [N][128] fp16 final x
    const int* __restrict__ edges,
    const float* __restrict__ edge_feats,
    const _Float16* __restrict__ w1p,         // packed B-frags, 32768
    const _Float16* __restrict__ w2p,         // packed B-frags, 8192
    const float* __restrict__ W1,             // fp32 (rows 256,257 used)
    const float* __restrict__ b1,
    const float* __restrict__ b2,
    const float* __restrict__ W3, const float* __restrict__ b3,
    float* __restrict__ out, int ne)
{
    __shared__ __align__(16) _Float16 h1s[4][16 * 128];
    const int wave = threadIdx.x >> 6;
    const int lane = threadIdx.x & 63;
    const int g = lane >> 4, c = lane & 15;
    const int base = (blockIdx.x * 4 + wave) * 16;
    if (base >= ne) return;

    const int erow = min(base + c, ne - 1);
    const int e0 = edges[erow * 2 + 0];
    const int e1 = edges[erow * 2 + 1];

    // ---- layer 1: [16,256] x [256,128]
    f32x4 C1[8];
    #pragma unroll
    for (int nt = 0; nt < 8; ++nt) C1[nt] = (f32x4){0.f, 0.f, 0.f, 0.f};
    #pragma unroll
    for (int kk = 0; kk < 8; ++kk) {
        const int node = (kk < 4) ? e0 : e1;
        const f16x8 a = *(const f16x8*)(xh + (size_t)node * 128 + (kk & 3) * 32 + g * 8);
        #pragma unroll
        for (int nt = 0; nt < 8; ++nt) {
            const f16x8 bf = *(const f16x8*)(w1p + ((nt * 8 + kk) << 9) + lane * 8);
            C1[nt] = __builtin_amdgcn_mfma_f32_16x16x32_f16(a, bf, C1[nt], 0, 0, 0);
        }
    }

    // ---- epilogue 1: + b1 + ef @ W1[256:258] ; relu ; fp16 -> swizzled LDS
    float ef0[4], ef1[4];
    #pragma unroll
    for (int r = 0; r < 4; ++r) {
        const int m = min(base + g * 4 + r, ne - 1);
        ef0[r] = edge_feats[(size_t)m * 2 + 0];
        ef1[r] = edge_feats[(size_t)m * 2 + 1];
    }
    char* const h1base = (char*)&h1s[wave][0];
    #pragma unroll
    for (int nt = 0; nt < 8; ++nt) {
        const int nn  = nt * 16 + c;
        const float bb  = b1[nn];
        const float wc0 = W1[256 * 128 + nn];
        const float wc1 = W1[257 * 128 + nn];
        #pragma unroll
        for (int r = 0; r < 4; ++r) {
            const int rr = g * 4 + r;
            const float h = fmaxf(C1[nt][r] + bb + ef0[r] * wc0 + ef1[r] * wc1, 0.0f);
            *(_Float16*)(h1base + rr * 256 + ((nn * 2) ^ (rr << 4))) = (_Float16)h;
        }
    }

    // ---- layer 2: [16,128] x [128,64]
    f32x4 C2[4];
    #pragma unroll
    for (int nt = 0; nt < 4; ++nt) C2[nt] = (f32x4){0.f, 0.f, 0.f, 0.f};
    #pragma unroll
    for (int kk = 0; kk < 4; ++kk) {
        const int k0b = kk * 64 + g * 16;
        const f16x8 a = *(const f16x8*)(h1base + c * 256 + (k0b ^ (c << 4)));
        #pragma unroll
        for (int nt = 0; nt < 4; ++nt) {
            const f16x8 bf = *(const f16x8*)(w2p + ((nt * 4 + kk) << 9) + lane * 8);
            C2[nt] = __builtin_amdgcn_mfma_f32_16x16x32_f16(a, bf, C2[nt], 0, 0, 0);
        }
    }

    // ---- layer 3: relu(h2) @ W3 + b3, 16-lane tree reduce
    const float bb3 = b3[0];
    #pragma unroll
    for (int r = 0; r < 4; ++r) {
        float acc = 0.0f;
        #pragma unroll
        for (int nt = 0; nt < 4; ++nt) {
            const int n2 = nt * 16 + c;
            acc += fmaxf(C2[nt][r] + b2[n2], 0.0f) * W3[n2];
        }
        acc += __shfl_xor(acc, 1);
        acc += __shfl_xor(acc, 2);
        acc += __shfl_xor(acc, 4);
        acc += __shfl_xor(acc, 8);
        const int m = base + g * 4 + r;
        if (c == 0 && m < ne) out[m] = acc + bb3;
    }
}

// ---------------------------------------------------------------------------
extern "C" void kernel_launch(void* const* d_in, const int* in_sizes, int n_in,
                              void* d_out, int out_size, void* d_ws, size_t ws_size,
                              hipStream_t stream) {
    const int*   type_idx   = (const int*)d_in[0];
    const int*   cat_idx    = (const int*)d_in[1];
    const int*   nbr_idx    = (const int*)d_in[2];
    const int*   nbr_mask   = (const int*)d_in[3];
    const int*   edges      = (const int*)d_in[4];
    const float* log_deg    = (const float*)d_in[5];
    const float* edge_feats = (const float*)d_in[6];
    const float* type_embed = (const float*)d_in[7];
    const float* cat0       = (const float*)d_in[8];
    const float* cat1       = (const float*)d_in[9];
    const float* deg_W      = (const float*)d_in[10];
    const float* deg_b      = (const float*)d_in[11];
    const float* proj_W     = (const float*)d_in[12];
    const float* proj_b     = (const float*)d_in[13];
    const float* attn_Wqkv  = (const float*)d_in[14];
    const float* attn_bqkv  = (const float*)d_in[15];
    const float* attn_Wo    = (const float*)d_in[16];
    const float* attn_bo    = (const float*)d_in[17];
    const float* eW1        = (const float*)d_in[18];
    const float* eb1        = (const float*)d_in[19];
    const float* eW2        = (const float*)d_in[20];
    const float* eb2        = (const float*)d_in[21];
    const float* eW3        = (const float*)d_in[22];
    const float* eb3        = (const float*)d_in[23];

    const int n  = in_sizes[0];        // N nodes
    const int ne = in_sizes[4] / 2;    // E edges
    float* out = (float*)d_out;

    // fp16 workspace buffers, each n*128 elements
    _Float16* xhA = (_Float16*)d_ws;
    _Float16* xhB = xhA + (size_t)n * HID;
    _Float16* qh  = xhB + (size_t)n * HID;
    _Float16* kh  = qh  + (size_t)n * HID;
    _Float16* vh  = kh  + (size_t)n * HID;
    _Float16* oh  = vh  + (size_t)n * HID;
    _Float16* wpk = oh  + (size_t)n * HID;   // packed weights, 237568 halves
    int* mask = (int*)(wpk + 237568);
    _Float16* wqkvp[3] = {wpk, wpk + 49152, wpk + 98304};
    _Float16* wop[3]   = {wpk + 147456, wpk + 163840, wpk + 180224};
    _Float16* w1p = wpk + 196608;
    _Float16* w2p = wpk + 229376;

    prep_kernel<<<dim3(928), dim3(256), 0, stream>>>(attn_Wqkv, attn_Wo, eW1, eW2, wpk);

    encode_kernel<<<dim3(1024), dim3(128), 0, stream>>>(
        type_idx, cat_idx, log_deg, type_embed, cat0, cat1,
        deg_W, deg_b, proj_W, proj_b, xhA, n);

    const int gemm_grid = (n + 63) / 64;    // 4 waves x 16 nodes
    const int attn_grid = (n + 15) / 16;    // 4 waves x 4 nodes

    qkv0_kernel<<<dim3(gemm_grid), dim3(256), 0, stream>>>(
        xhA, wqkvp[0], attn_bqkv, qh, kh, vh, n);
    attn_kernel<<<dim3(attn_grid), dim3(256), 0, stream>>>(
        qh, kh, vh, nbr_idx, nbr_mask, oh, mask, n);

    // layer transitions: (oh,mask,x_prev) -> x_next (+ qkv for next layer)
    projqkv_kernel<<<dim3(gemm_grid), dim3(256), 0, stream>>>(
        oh, mask, xhA, wop[0], attn_bo, wqkvp[1], attn_bqkv + 384,
        xhB, qh, kh, vh, 1, n);
    attn_kernel<<<dim3(attn_grid), dim3(256), 0, stream>>>(
        qh, kh, vh, nbr_idx, nbr_mask, oh, mask, n);

    projqkv_kernel<<<dim3(gemm_grid), dim3(256), 0, stream>>>(
        oh, mask, xhB, wop[1], attn_bo + 128, wqkvp[2], attn_bqkv + 768,
        xhA, qh, kh, vh, 1, n);
    attn_kernel<<<dim3(attn_grid), dim3(256), 0, stream>>>(
        qh, kh, vh, nbr_idx, nbr_mask, oh, mask, n);

    projqkv_kernel<<<dim3(gemm_grid), dim3(256), 0, stream>>>(
        oh, mask, xhA, wop[2], attn_bo + 256, nullptr, nullptr,
        xhB, nullptr, nullptr, nullptr, 0, n);

    const int edge_grid = (ne + 63) / 64;   // 4 waves x 16 edges
    edge_mfma_kernel<<<dim3(edge_grid), dim3(256), 0, stream>>>(
        xhB, edges, edge_feats, w1p, w2p, eW1, eb1, eb2, eW3, eb3, out, ne);
}

// Round 6
// 459.410 us; speedup vs baseline: 3.1407x; 1.1467x over previous
//
#include <hip/hip_runtime.h>
#include <math.h>

#define HID 128

typedef _Float16 f16x8 __attribute__((ext_vector_type(8)));
typedef float    f32x4 __attribute__((ext_vector_type(4)));

static __device__ __forceinline__ float h_lo(unsigned p) {
    return (float)__builtin_bit_cast(_Float16, (unsigned short)p);
}
static __device__ __forceinline__ float h_hi(unsigned p) {
    return (float)__builtin_bit_cast(_Float16, (unsigned short)(p >> 16));
}
static __device__ __forceinline__ unsigned pack2h(float x, float y) {
    const unsigned short lx = __builtin_bit_cast(unsigned short, (_Float16)x);
    const unsigned short ly = __builtin_bit_cast(unsigned short, (_Float16)y);
    return ((unsigned)ly << 16) | lx;
}

// ---------------------------------------------------------------------------
// Kernel 0: pack ALL GEMM weights into fp16 MFMA B-fragment order.
// B-frag layout: [NT][KK][64 lane][8 j]; elem = W[k = KK*32+(ln>>4)*8+j][n = NT*16+(ln&15)]
// regions: wqkvp 3x[24][4] | wop 3x[8][4] | w1p [8][8] | w2p [4][4] | wprojp [8][5]
// ---------------------------------------------------------------------------
__global__ __launch_bounds__(256) void prep_kernel(
    const float* __restrict__ Wqkv, const float* __restrict__ Wo,
    const float* __restrict__ W1, const float* __restrict__ W2,
    const float* __restrict__ Wproj,
    _Float16* __restrict__ dst)
{
    const int idx = blockIdx.x * 256 + threadIdx.x;
    if (idx < 147456) {                     // wqkvp: 3 layers x 24nt x 4kk
        const int l = idx / 49152, t = idx % 49152;
        const int j = t & 7, ln = (t >> 3) & 63, kk = (t >> 9) & 3, nt = t >> 11;
        const int k = kk * 32 + (ln >> 4) * 8 + j, n = nt * 16 + (ln & 15);
        dst[idx] = (_Float16)Wqkv[((size_t)l * 128 + k) * 384 + n];
    } else if (idx < 196608) {              // wop: 3 layers x 8nt x 4kk
        const int t0 = idx - 147456;
        const int l = t0 / 16384, t = t0 % 16384;
        const int j = t & 7, ln = (t >> 3) & 63, kk = (t >> 9) & 3, nt = t >> 11;
        const int k = kk * 32 + (ln >> 4) * 8 + j, n = nt * 16 + (ln & 15);
        dst[idx] = (_Float16)Wo[((size_t)l * 128 + k) * 128 + n];
    } else if (idx < 229376) {              // w1p: 8nt x 8kk (k<256)
        const int t = idx - 196608;
        const int j = t & 7, ln = (t >> 3) & 63, kk = (t >> 9) & 7, nt = t >> 12;
        const int k = kk * 32 + (ln >> 4) * 8 + j, n = nt * 16 + (ln & 15);
        dst[idx] = (_Float16)W1[k * 128 + n];
    } else if (idx < 237568) {              // w2p: 4nt x 4kk
        const int t = idx - 229376;
        const int j = t & 7, ln = (t >> 3) & 63, kk = (t >> 9) & 3, nt = t >> 11;
        const int k = kk * 32 + (ln >> 4) * 8 + j, n = nt * 16 + (ln & 15);
        dst[idx] = (_Float16)W2[k * 64 + n];
    } else if (idx < 258048) {              // wprojp: 8nt x 5kk (k<160)
        const int t = idx - 237568;
        const int j = t & 7, ln = (t >> 3) & 63;
        const int blk = t >> 9;             // nt*5 + kk
        const int kk = blk % 5, nt = blk / 5;
        const int k = kk * 32 + (ln >> 4) * 8 + j, n = nt * 16 + (ln & 15);
        dst[idx] = (_Float16)Wproj[k * 128 + n];
    }
}

// tile swizzle: byte addr = row*256 + ((col*2) ^ (row<<4)), rows 0..15, cols 0..127
// full-coverage coalesced tile->global write:
// 4 iters x 64 lanes = 256 (row, 16B-chunk) pairs = 16 rows x 16 chunks.
#define TILE_STORE(dst)                                                        \
    _Pragma("unroll")                                                          \
    for (int t = 0; t < 4; ++t) {                                              \
        const int lr  = t * 4 + (lane >> 4);                                   \
        const int j16 = lane & 15;                                             \
        const f16x8 v = *(const f16x8*)(tb + lr * 256 + ((j16 * 16) ^ (lr << 4))); \
        if (base + lr < n)                                                     \
            *(f16x8*)((dst) + (size_t)(base + lr) * 128 + j16 * 8) = v;        \
    }

// qkv GEMM from A-frags a2[4] (K=128) -> q/k/v buffers, via swizzled tile
#define QKV_PHASE(A2, WQ, BQKV)                                                \
    {                                                                          \
        _Float16* outs[3] = {qh, kh, vh};                                      \
        _Pragma("unroll")                                                      \
        for (int part = 0; part < 3; ++part) {                                 \
            f32x4 C[8];                                                        \
            _Pragma("unroll")                                                  \
            for (int nt = 0; nt < 8; ++nt) C[nt] = (f32x4){0.f, 0.f, 0.f, 0.f};\
            _Pragma("unroll")                                                  \
            for (int kk = 0; kk < 4; ++kk) {                                   \
                _Pragma("unroll")                                              \
                for (int nt = 0; nt < 8; ++nt) {                               \
                    const f16x8 bf = *(const f16x8*)((WQ) + (((part * 8 + nt) * 4 + kk) << 9) + lane * 8); \
                    C[nt] = __builtin_amdgcn_mfma_f32_16x16x32_f16((A2)[kk], bf, C[nt], 0, 0, 0); \
                }                                                              \
            }                                                                  \
            _Pragma("unroll")                                                  \
            for (int nt = 0; nt < 8; ++nt) {                                   \
                const int nn = nt * 16 + c;                                    \
                const float bb = (BQKV)[part * 128 + nn];                      \
                _Pragma("unroll")                                              \
                for (int r = 0; r < 4; ++r) {                                  \
                    const int rr = g * 4 + r;                                  \
                    *(_Float16*)(tb + rr * 256 + ((nn * 2) ^ (rr << 4))) = (_Float16)(C[nt][r] + bb); \
                }                                                              \
            }                                                                  \
            _Float16* const dst = outs[part];                                  \
            TILE_STORE(dst)                                                    \
        }                                                                      \
    }

// ---------------------------------------------------------------------------
// Kernel 1: FUSED node-encode + layer-0 qkv.  Wave = 16 nodes.
// A-frags (K=160) built per-lane from embed tables; proj via 5kk x 8nt MFMAs;
// x tile -> xh + immediately qkv phase (identical to projqkv phase 2).
// ---------------------------------------------------------------------------
__global__ __launch_bounds__(256) void encode_qkv_kernel(
    const int* __restrict__ type_idx, const int* __restrict__ cat_idx,
    const float* __restrict__ log_deg,
    const float* __restrict__ type_embed, const float* __restrict__ cat0,
    const float* __restrict__ cat1, const float* __restrict__ deg_W,
    const float* __restrict__ deg_b,
    const _Float16* __restrict__ wprojp, const float* __restrict__ proj_b,
    const _Float16* __restrict__ wq, const float* __restrict__ bqkv,
    _Float16* __restrict__ xh,
    _Float16* __restrict__ qh, _Float16* __restrict__ kh, _Float16* __restrict__ vh,
    int n)
{
    __shared__ __align__(16) _Float16 tile[4][16 * 128];
    const int wave = threadIdx.x >> 6;
    const int lane = threadIdx.x & 63;
    const int g = lane >> 4, c = lane & 15;
    const int base = (blockIdx.x * 4 + wave) * 16;
    if (base >= n) return;
    const int arow = min(base + c, n - 1);
    char* const tb = (char*)&tile[wave][0];

    // ---- build A-frags for K=160 feats
    const int  ti = type_idx[arow];
    const int  c0 = cat_idx[arow * 2 + 0];
    const int  c1 = cat_idx[arow * 2 + 1];
    const float ld = log_deg[arow];
    f16x8 a[5];
    {
        const float* srcs[4] = {
            type_embed + ti * 64 + g * 8,        // kk=0: feats[0..31]
            type_embed + ti * 64 + 32 + g * 8,   // kk=1: feats[32..63]
            cat0 + c0 * 32 + g * 8,              // kk=2: feats[64..95]
            cat1 + c1 * 32 + g * 8,              // kk=3: feats[96..127]
        };
        #pragma unroll
        for (int kk = 0; kk < 4; ++kk) {
            const float4 v0 = *(const float4*)(srcs[kk]);
            const float4 v1 = *(const float4*)(srcs[kk] + 4);
            a[kk] = (f16x8){(_Float16)v0.x, (_Float16)v0.y, (_Float16)v0.z, (_Float16)v0.w,
                            (_Float16)v1.x, (_Float16)v1.y, (_Float16)v1.z, (_Float16)v1.w};
        }
        const float4 w0 = *(const float4*)(deg_W + g * 8);
        const float4 w1 = *(const float4*)(deg_W + g * 8 + 4);
        const float4 d0 = *(const float4*)(deg_b + g * 8);
        const float4 d1 = *(const float4*)(deg_b + g * 8 + 4);
        a[4] = (f16x8){
            (_Float16)fmaxf(ld * w0.x + d0.x, 0.f), (_Float16)fmaxf(ld * w0.y + d0.y, 0.f),
            (_Float16)fmaxf(ld * w0.z + d0.z, 0.f), (_Float16)fmaxf(ld * w0.w + d0.w, 0.f),
            (_Float16)fmaxf(ld * w1.x + d1.x, 0.f), (_Float16)fmaxf(ld * w1.y + d1.y, 0.f),
            (_Float16)fmaxf(ld * w1.z + d1.z, 0.f), (_Float16)fmaxf(ld * w1.w + d1.w, 0.f)};
    }

    // ---- proj: 5kk x 8nt MFMAs
    f32x4 Cp[8];
    #pragma unroll
    for (int nt = 0; nt < 8; ++nt) Cp[nt] = (f32x4){0.f, 0.f, 0.f, 0.f};
    #pragma unroll
    for (int kk = 0; kk < 5; ++kk) {
        #pragma unroll
        for (int nt = 0; nt < 8; ++nt) {
            const f16x8 bf = *(const f16x8*)(wprojp + ((nt * 5 + kk) << 9) + lane * 8);
            Cp[nt] = __builtin_amdgcn_mfma_f32_16x16x32_f16(a[kk], bf, Cp[nt], 0, 0, 0);
        }
    }
    #pragma unroll
    for (int nt = 0; nt < 8; ++nt) {
        const int nn = nt * 16 + c;
        const float bb = proj_b[nn];
        #pragma unroll
        for (int r = 0; r < 4; ++r) {
            const int rr = g * 4 + r;
            *(_Float16*)(tb + rr * 256 + ((nn * 2) ^ (rr << 4))) = (_Float16)(Cp[nt][r] + bb);
        }
    }
    TILE_STORE(xh)

    // ---- layer-0 qkv from the tile
    f16x8 a2[4];
    #pragma unroll
    for (int kk = 0; kk < 4; ++kk)
        a2[kk] = *(const f16x8*)(tb + c * 256 + ((kk * 64 + g * 16) ^ (c << 4)));
    QKV_PHASE(a2, wq, bqkv)
}

// ---------------------------------------------------------------------------
// Kernel 2: fused out-proj (+fallback+relu) and optional next-layer qkv.
// x_next = relu(mask ? o@Wo + bo : x_prev);  then qkv = x_next @ Wqkv_next.
// ---------------------------------------------------------------------------
__global__ __launch_bounds__(256) void projqkv_kernel(
    const _Float16* __restrict__ oh, const int* __restrict__ mask,
    const _Float16* __restrict__ xh_prev,
    const _Float16* __restrict__ wo, const float* __restrict__ bo,
    const _Float16* __restrict__ wq, const float* __restrict__ bqkv,
    _Float16* __restrict__ xh_next,
    _Float16* __restrict__ qh, _Float16* __restrict__ kh, _Float16* __restrict__ vh,
    int do_qkv, int n)
{
    __shared__ __align__(16) _Float16 tile[4][16 * 128];
    const int wave = threadIdx.x >> 6;
    const int lane = threadIdx.x & 63;
    const int g = lane >> 4, c = lane & 15;
    const int base = (blockIdx.x * 4 + wave) * 16;
    if (base >= n) return;
    const int arow = min(base + c, n - 1);
    char* const tb = (char*)&tile[wave][0];

    // ---- phase 1: o @ Wo
    f32x4 Cp[8];
    #pragma unroll
    for (int nt = 0; nt < 8; ++nt) Cp[nt] = (f32x4){0.f, 0.f, 0.f, 0.f};
    #pragma unroll
    for (int kk = 0; kk < 4; ++kk) {
        const f16x8 a = *(const f16x8*)(oh + (size_t)arow * 128 + kk * 32 + g * 8);
        #pragma unroll
        for (int nt = 0; nt < 8; ++nt) {
            const f16x8 bf = *(const f16x8*)(wo + ((nt * 4 + kk) << 9) + lane * 8);
            Cp[nt] = __builtin_amdgcn_mfma_f32_16x16x32_f16(a, bf, Cp[nt], 0, 0, 0);
        }
    }
    int mk[4]; int rrow[4];
    #pragma unroll
    for (int r = 0; r < 4; ++r) {
        rrow[r] = min(base + g * 4 + r, n - 1);
        mk[r] = mask[rrow[r]];
    }
    #pragma unroll
    for (int nt = 0; nt < 8; ++nt) {
        const int nn = nt * 16 + c;
        const float bb = bo[nn];
        #pragma unroll
        for (int r = 0; r < 4; ++r) {
            float val = Cp[nt][r] + bb;
            if (!mk[r]) val = (float)xh_prev[(size_t)rrow[r] * 128 + nn];
            val = fmaxf(val, 0.0f);
            const int rr = g * 4 + r;
            *(_Float16*)(tb + rr * 256 + ((nn * 2) ^ (rr << 4))) = (_Float16)val;
        }
    }
    // write x_next coalesced (full 128 cols)
    TILE_STORE(xh_next)
    if (!do_qkv) return;

    // ---- phase 2: x_next @ Wqkv (A-frags read from tile BEFORE overwriting it)
    f16x8 a2[4];
    #pragma unroll
    for (int kk = 0; kk < 4; ++kk)
        a2[kk] = *(const f16x8*)(tb + c * 256 + ((kk * 64 + g * 16) ^ (c << 4)));
    QKV_PHASE(a2, wq, bqkv)
}

// ---------------------------------------------------------------------------
// Kernel 3: attention core: scores + softmax + PV.  Writes o (fp16) + mask.
// wave per node-group of 4; lane covers dims (2*lane, 2*lane+1).
// ---------------------------------------------------------------------------
__global__ __launch_bounds__(256) void attn_kernel(
    const _Float16* __restrict__ qh, const _Float16* __restrict__ kh,
    const _Float16* __restrict__ vh,
    const int* __restrict__ nbr_idx, const int* __restrict__ nbr_mask,
    _Float16* __restrict__ oh, int* __restrict__ mask_out, int n)
{
    const int wave = threadIdx.x >> 6;
    const int lane = threadIdx.x & 63;
    const float scale = 0.17677669529663687f;   // 1/sqrt(32)
    const int base = (blockIdx.x * 4 + wave) * 4;
    if (base >= n) return;
    const int nbc = min(4, n - base);
    for (int nb = 0; nb < nbc; ++nb) {
        const int node = base + nb;
        const unsigned qq = *(const unsigned*)(qh + (size_t)node * HID + lane * 2);
        const float qx = h_lo(qq), qy = h_hi(qq);
        float s[17];
        int cix[17];
        int anyn = 0;
        #pragma unroll
        for (int c = 0; c < 17; ++c) {
            int cidx, valid;
            if (c == 0) { cidx = node; valid = 1; }
            else {
                cidx  = nbr_idx[node * 16 + (c - 1)];
                valid = nbr_mask[node * 16 + (c - 1)];
                anyn |= valid;
            }
            cix[c] = cidx;
            const unsigned kk = *(const unsigned*)(kh + (size_t)cidx * HID + lane * 2);
            float p = qx * h_lo(kk) + qy * h_hi(kk);
            p += __shfl_xor(p, 1);
            p += __shfl_xor(p, 2);
            p += __shfl_xor(p, 4);
            p += __shfl_xor(p, 8);
            s[c] = valid ? p * scale : -1e9f;
        }
        if (lane == 0) mask_out[node] = anyn;
        float mx = s[0];
        #pragma unroll
        for (int c = 1; c < 17; ++c) mx = fmaxf(mx, s[c]);
        float sum = 0.0f;
        #pragma unroll
        for (int c = 0; c < 17; ++c) { s[c] = __expf(s[c] - mx); sum += s[c]; }
        const float inv = 1.0f / sum;
        float ox = 0.0f, oy = 0.0f;
        #pragma unroll
        for (int c = 0; c < 17; ++c) {
            const unsigned vv = *(const unsigned*)(vh + (size_t)cix[c] * HID + lane * 2);
            const float a = s[c] * inv;
            ox += a * h_lo(vv);
            oy += a * h_hi(vv);
        }
        *(unsigned*)(oh + (size_t)node * HID + lane * 2) = pack2h(ox, oy);
    }
}

// ---------------------------------------------------------------------------
// Kernel 4: edge MLP via fp16 MFMA.
// ---------------------------------------------------------------------------
__global__ __launch_bounds__(256) void edge_mfma_kernel(
    const _Float16* __restrict__ xh,          // [N][128] fp16 final x
    const int* __restrict__ edges,
    const float* __restrict__ edge_feats,
    const _Float16* __restrict__ w1p,         // packed B-frags, 32768
    const _Float16* __restrict__ w2p,         // packed B-frags, 8192
    const float* __restrict__ W1,             // fp32 (rows 256,257 used)
    const float* __restrict__ b1,
    const float* __restrict__ b2,
    const float* __restrict__ W3, const float* __restrict__ b3,
    float* __restrict__ out, int ne)
{
    __shared__ __align__(16) _Float16 h1s[4][16 * 128];
    const int wave = threadIdx.x >> 6;
    const int lane = threadIdx.x & 63;
    const int g = lane >> 4, c = lane & 15;
    const int base = (blockIdx.x * 4 + wave) * 16;
    if (base >= ne) return;

    const int erow = min(base + c, ne - 1);
    const int e0 = edges[erow * 2 + 0];
    const int e1 = edges[erow * 2 + 1];

    // ---- layer 1: [16,256] x [256,128]
    f32x4 C1[8];
    #pragma unroll
    for (int nt = 0; nt < 8; ++nt) C1[nt] = (f32x4){0.f, 0.f, 0.f, 0.f};
    #pragma unroll
    for (int kk = 0; kk < 8; ++kk) {
        const int node = (kk < 4) ? e0 : e1;
        const f16x8 a = *(const f16x8*)(xh + (size_t)node * 128 + (kk & 3) * 32 + g * 8);
        #pragma unroll
        for (int nt = 0; nt < 8; ++nt) {
            const f16x8 bf = *(const f16x8*)(w1p + ((nt * 8 + kk) << 9) + lane * 8);
            C1[nt] = __builtin_amdgcn_mfma_f32_16x16x32_f16(a, bf, C1[nt], 0, 0, 0);
        }
    }

    // ---- epilogue 1: + b1 + ef @ W1[256:258] ; relu ; fp16 -> swizzled LDS
    float ef0[4], ef1[4];
    #pragma unroll
    for (int r = 0; r < 4; ++r) {
        const int m = min(base + g * 4 + r, ne - 1);
        ef0[r] = edge_feats[(size_t)m * 2 + 0];
        ef1[r] = edge_feats[(size_t)m * 2 + 1];
    }
    char* const h1base = (char*)&h1s[wave][0];
    #pragma unroll
    for (int nt = 0; nt < 8; ++nt) {
        const int nn  = nt * 16 + c;
        const float bb  = b1[nn];
        const float wc0 = W1[256 * 128 + nn];
        const float wc1 = W1[257 * 128 + nn];
        #pragma unroll
        for (int r = 0; r < 4; ++r) {
            const int rr = g * 4 + r;
            const float h = fmaxf(C1[nt][r] + bb + ef0[r] * wc0 + ef1[r] * wc1, 0.0f);
            *(_Float16*)(h1base + rr * 256 + ((nn * 2) ^ (rr << 4))) = (_Float16)h;
        }
    }

    // ---- layer 2: [16,128] x [128,64]
    f32x4 C2[4];
    #pragma unroll
    for (int nt = 0; nt < 4; ++nt) C2[nt] = (f32x4){0.f, 0.f, 0.f, 0.f};
    #pragma unroll
    for (int kk = 0; kk < 4; ++kk) {
        const int k0b = kk * 64 + g * 16;
        const f16x8 a = *(const f16x8*)(h1base + c * 256 + (k0b ^ (c << 4)));
        #pragma unroll
        for (int nt = 0; nt < 4; ++nt) {
            const f16x8 bf = *(const f16x8*)(w2p + ((nt * 4 + kk) << 9) + lane * 8);
            C2[nt] = __builtin_amdgcn_mfma_f32_16x16x32_f16(a, bf, C2[nt], 0, 0, 0);
        }
    }

    // ---- layer 3: relu(h2) @ W3 + b3, 16-lane tree reduce
    const float bb3 = b3[0];
    #pragma unroll
    for (int r = 0; r < 4; ++r) {
        float acc = 0.0f;
        #pragma unroll
        for (int nt = 0; nt < 4; ++nt) {
            const int n2 = nt * 16 + c;
            acc += fmaxf(C2[nt][r] + b2[n2], 0.0f) * W3[n2];
        }
        acc += __shfl_xor(acc, 1);
        acc += __shfl_xor(acc, 2);
        acc += __shfl_xor(acc, 4);
        acc += __shfl_xor(acc, 8);
        const int m = base + g * 4 + r;
        if (c == 0 && m < ne) out[m] = acc + bb3;
    }
}

// ---------------------------------------------------------------------------
extern "C" void kernel_launch(void* const* d_in, const int* in_sizes, int n_in,
                              void* d_out, int out_size, void* d_ws, size_t ws_size,
                              hipStream_t stream) {
    const int*   type_idx   = (const int*)d_in[0];
    const int*   cat_idx    = (const int*)d_in[1];
    const int*   nbr_idx    = (const int*)d_in[2];
    const int*   nbr_mask   = (const int*)d_in[3];
    const int*   edges      = (const int*)d_in[4];
    const float* log_deg    = (const float*)d_in[5];
    const float* edge_feats = (const float*)d_in[6];
    const float* type_embed = (const float*)d_in[7];
    const float* cat0       = (const float*)d_in[8];
    const float* cat1       = (const float*)d_in[9];
    const float* deg_W      = (const float*)d_in[10];
    const float* deg_b      = (const float*)d_in[11];
    const float* proj_W     = (const float*)d_in[12];
    const float* proj_b     = (const float*)d_in[13];
    const float* attn_Wqkv  = (const float*)d_in[14];
    const float* attn_bqkv  = (const float*)d_in[15];
    const float* attn_Wo    = (const float*)d_in[16];
    const float* attn_bo    = (const float*)d_in[17];
    const float* eW1        = (const float*)d_in[18];
    const float* eb1        = (const float*)d_in[19];
    const float* eW2        = (const float*)d_in[20];
    const float* eb2        = (const float*)d_in[21];
    const float* eW3        = (const float*)d_in[22];
    const float* eb3        = (const float*)d_in[23];

    const int n  = in_sizes[0];        // N nodes
    const int ne = in_sizes[4] / 2;    // E edges
    float* out = (float*)d_out;

    // fp16 workspace buffers, each n*128 elements
    _Float16* xhA = (_Float16*)d_ws;
    _Float16* xhB = xhA + (size_t)n * HID;
    _Float16* qh  = xhB + (size_t)n * HID;
    _Float16* kh  = qh  + (size_t)n * HID;
    _Float16* vh  = kh  + (size_t)n * HID;
    _Float16* oh  = vh  + (size_t)n * HID;
    _Float16* wpk = oh  + (size_t)n * HID;   // packed weights, 258048 halves
    int* mask = (int*)(wpk + 258048);
    _Float16* wqkvp[3] = {wpk, wpk + 49152, wpk + 98304};
    _Float16* wop[3]   = {wpk + 147456, wpk + 163840, wpk + 180224};
    _Float16* w1p    = wpk + 196608;
    _Float16* w2p    = wpk + 229376;
    _Float16* wprojp = wpk + 237568;

    prep_kernel<<<dim3(1008), dim3(256), 0, stream>>>(
        attn_Wqkv, attn_Wo, eW1, eW2, proj_W, wpk);

    const int gemm_grid = (n + 63) / 64;    // 4 waves x 16 nodes
    const int attn_grid = (n + 15) / 16;    // 4 waves x 4 nodes

    // fused encode + layer-0 qkv
    encode_qkv_kernel<<<dim3(gemm_grid), dim3(256), 0, stream>>>(
        type_idx, cat_idx, log_deg, type_embed, cat0, cat1, deg_W, deg_b,
        wprojp, proj_b, wqkvp[0], attn_bqkv,
        xhA, qh, kh, vh, n);
    attn_kernel<<<dim3(attn_grid), dim3(256), 0, stream>>>(
        qh, kh, vh, nbr_idx, nbr_mask, oh, mask, n);

    // layer transitions: (oh,mask,x_prev) -> x_next (+ qkv for next layer)
    projqkv_kernel<<<dim3(gemm_grid), dim3(256), 0, stream>>>(
        oh, mask, xhA, wop[0], attn_bo, wqkvp[1], attn_bqkv + 384,
        xhB, qh, kh, vh, 1, n);
    attn_kernel<<<dim3(attn_grid), dim3(256), 0, stream>>>(
        qh, kh, vh, nbr_idx, nbr_mask, oh, mask, n);

    projqkv_kernel<<<dim3(gemm_grid), dim3(256), 0, stream>>>(
        oh, mask, xhB, wop[1], attn_bo + 128, wqkvp[2], attn_bqkv + 768,
        xhA, qh, kh, vh, 1, n);
    attn_kernel<<<dim3(attn_grid), dim3(256), 0, stream>>>(
        qh, kh, vh, nbr_idx, nbr_mask, oh, mask, n);

    projqkv_kernel<<<dim3(gemm_grid), dim3(256), 0, stream>>>(
        oh, mask, xhA, wop[2], attn_bo + 256, nullptr, nullptr,
        xhB, nullptr, nullptr, nullptr, 0, n);

    const int edge_grid = (ne + 63) / 64;   // 4 waves x 16 edges
    edge_mfma_kernel<<<dim3(edge_grid), dim3(256), 0, stream>>>(
        xhB, edges, edge_feats, w1p, w2p, eW1, eb1, eb2, eW3, eb3, out, ne);
}

// Round 7
// 444.999 us; speedup vs baseline: 3.2424x; 1.0324x over previous
//
#include <hip/hip_runtime.h>
#include <math.h>

#define HID 128

typedef _Float16 f16x8 __attribute__((ext_vector_type(8)));
typedef float    f32x4 __attribute__((ext_vector_type(4)));

static __device__ __forceinline__ float h_lo(unsigned p) {
    return (float)__builtin_bit_cast(_Float16, (unsigned short)p);
}
static __device__ __forceinline__ float h_hi(unsigned p) {
    return (float)__builtin_bit_cast(_Float16, (unsigned short)(p >> 16));
}
static __device__ __forceinline__ unsigned pack2h(float x, float y) {
    const unsigned short lx = __builtin_bit_cast(unsigned short, (_Float16)x);
    const unsigned short ly = __builtin_bit_cast(unsigned short, (_Float16)y);
    return ((unsigned)ly << 16) | lx;
}

// ---------------------------------------------------------------------------
// Kernel 0: pack ALL GEMM weights into fp16 MFMA B-fragment order.
// B-frag layout: [NT][KK][64 lane][8 j]; elem = W[k = KK*32+(ln>>4)*8+j][n = NT*16+(ln&15)]
// regions: wqkvp 3x[24][4] | wop 3x[8][4] | w1p [8][8] | w2p [4][4] | wprojp [8][5]
// ---------------------------------------------------------------------------
__global__ __launch_bounds__(256) void prep_kernel(
    const float* __restrict__ Wqkv, const float* __restrict__ Wo,
    const float* __restrict__ W1, const float* __restrict__ W2,
    const float* __restrict__ Wproj,
    _Float16* __restrict__ dst)
{
    const int idx = blockIdx.x * 256 + threadIdx.x;
    if (idx < 147456) {                     // wqkvp: 3 layers x 24nt x 4kk
        const int l = idx / 49152, t = idx % 49152;
        const int j = t & 7, ln = (t >> 3) & 63, kk = (t >> 9) & 3, nt = t >> 11;
        const int k = kk * 32 + (ln >> 4) * 8 + j, n = nt * 16 + (ln & 15);
        dst[idx] = (_Float16)Wqkv[((size_t)l * 128 + k) * 384 + n];
    } else if (idx < 196608) {              // wop: 3 layers x 8nt x 4kk
        const int t0 = idx - 147456;
        const int l = t0 / 16384, t = t0 % 16384;
        const int j = t & 7, ln = (t >> 3) & 63, kk = (t >> 9) & 3, nt = t >> 11;
        const int k = kk * 32 + (ln >> 4) * 8 + j, n = nt * 16 + (ln & 15);
        dst[idx] = (_Float16)Wo[((size_t)l * 128 + k) * 128 + n];
    } else if (idx < 229376) {              // w1p: 8nt x 8kk (k<256)
        const int t = idx - 196608;
        const int j = t & 7, ln = (t >> 3) & 63, kk = (t >> 9) & 7, nt = t >> 12;
        const int k = kk * 32 + (ln >> 4) * 8 + j, n = nt * 16 + (ln & 15);
        dst[idx] = (_Float16)W1[k * 128 + n];
    } else if (idx < 237568) {              // w2p: 4nt x 4kk
        const int t = idx - 229376;
        const int j = t & 7, ln = (t >> 3) & 63, kk = (t >> 9) & 3, nt = t >> 11;
        const int k = kk * 32 + (ln >> 4) * 8 + j, n = nt * 16 + (ln & 15);
        dst[idx] = (_Float16)W2[k * 64 + n];
    } else if (idx < 258048) {              // wprojp: 8nt x 5kk (k<160)
        const int t = idx - 237568;
        const int j = t & 7, ln = (t >> 3) & 63;
        const int blk = t >> 9;             // nt*5 + kk
        const int kk = blk % 5, nt = blk / 5;
        const int k = kk * 32 + (ln >> 4) * 8 + j, n = nt * 16 + (ln & 15);
        dst[idx] = (_Float16)Wproj[k * 128 + n];
    }
}

// tile swizzle: byte addr = row*256 + ((col*2) ^ (row<<4)), rows 0..15, cols 0..127
// full-coverage coalesced tile->global write, parameterized row stride (halves).
#define TILE_STORE_S(dst, rowstride)                                           \
    _Pragma("unroll")                                                          \
    for (int t = 0; t < 4; ++t) {                                              \
        const int lr  = t * 4 + (lane >> 4);                                   \
        const int j16 = lane & 15;                                             \
        const f16x8 v = *(const f16x8*)(tb + lr * 256 + ((j16 * 16) ^ (lr << 4))); \
        if (base + lr < n)                                                     \
            *(f16x8*)((dst) + (size_t)(base + lr) * (rowstride) + j16 * 8) = v;\
    }

// qkv GEMM from A-frags a2[4] (K=128) -> q (stride 128) + interleaved kv rows
// kvh[node][0..127]=k, [128..255]=v  (one 512B row per node)
#define QKV_PHASE(A2, WQ, BQKV)                                                \
    {                                                                          \
        _Pragma("unroll")                                                      \
        for (int part = 0; part < 3; ++part) {                                 \
            f32x4 C[8];                                                        \
            _Pragma("unroll")                                                  \
            for (int nt = 0; nt < 8; ++nt) C[nt] = (f32x4){0.f, 0.f, 0.f, 0.f};\
            _Pragma("unroll")                                                  \
            for (int kk = 0; kk < 4; ++kk) {                                   \
                _Pragma("unroll")                                              \
                for (int nt = 0; nt < 8; ++nt) {                               \
                    const f16x8 bf = *(const f16x8*)((WQ) + (((part * 8 + nt) * 4 + kk) << 9) + lane * 8); \
                    C[nt] = __builtin_amdgcn_mfma_f32_16x16x32_f16((A2)[kk], bf, C[nt], 0, 0, 0); \
                }                                                              \
            }                                                                  \
            _Pragma("unroll")                                                  \
            for (int nt = 0; nt < 8; ++nt) {                                   \
                const int nn = nt * 16 + c;                                    \
                const float bb = (BQKV)[part * 128 + nn];                      \
                _Pragma("unroll")                                              \
                for (int r = 0; r < 4; ++r) {                                  \
                    const int rr = g * 4 + r;                                  \
                    *(_Float16*)(tb + rr * 256 + ((nn * 2) ^ (rr << 4))) = (_Float16)(C[nt][r] + bb); \
                }                                                              \
            }                                                                  \
            if (part == 0)      { TILE_STORE_S(qh, 128) }                      \
            else if (part == 1) { TILE_STORE_S(kvh, 256) }                     \
            else                { TILE_STORE_S(kvh + 128, 256) }               \
        }                                                                      \
    }

// ---------------------------------------------------------------------------
// Kernel 1: FUSED node-encode + layer-0 qkv.  Wave = 16 nodes.
// ---------------------------------------------------------------------------
__global__ __launch_bounds__(256) void encode_qkv_kernel(
    const int* __restrict__ type_idx, const int* __restrict__ cat_idx,
    const float* __restrict__ log_deg,
    const float* __restrict__ type_embed, const float* __restrict__ cat0,
    const float* __restrict__ cat1, const float* __restrict__ deg_W,
    const float* __restrict__ deg_b,
    const _Float16* __restrict__ wprojp, const float* __restrict__ proj_b,
    const _Float16* __restrict__ wq, const float* __restrict__ bqkv,
    _Float16* __restrict__ xh,
    _Float16* __restrict__ qh, _Float16* __restrict__ kvh,
    int n)
{
    __shared__ __align__(16) _Float16 tile[4][16 * 128];
    const int wave = threadIdx.x >> 6;
    const int lane = threadIdx.x & 63;
    const int g = lane >> 4, c = lane & 15;
    const int base = (blockIdx.x * 4 + wave) * 16;
    if (base >= n) return;
    const int arow = min(base + c, n - 1);
    char* const tb = (char*)&tile[wave][0];

    // ---- build A-frags for K=160 feats
    const int  ti = type_idx[arow];
    const int  c0 = cat_idx[arow * 2 + 0];
    const int  c1 = cat_idx[arow * 2 + 1];
    const float ld = log_deg[arow];
    f16x8 a[5];
    {
        const float* srcs[4] = {
            type_embed + ti * 64 + g * 8,        // kk=0: feats[0..31]
            type_embed + ti * 64 + 32 + g * 8,   // kk=1: feats[32..63]
            cat0 + c0 * 32 + g * 8,              // kk=2: feats[64..95]
            cat1 + c1 * 32 + g * 8,              // kk=3: feats[96..127]
        };
        #pragma unroll
        for (int kk = 0; kk < 4; ++kk) {
            const float4 v0 = *(const float4*)(srcs[kk]);
            const float4 v1 = *(const float4*)(srcs[kk] + 4);
            a[kk] = (f16x8){(_Float16)v0.x, (_Float16)v0.y, (_Float16)v0.z, (_Float16)v0.w,
                            (_Float16)v1.x, (_Float16)v1.y, (_Float16)v1.z, (_Float16)v1.w};
        }
        const float4 w0 = *(const float4*)(deg_W + g * 8);
        const float4 w1 = *(const float4*)(deg_W + g * 8 + 4);
        const float4 d0 = *(const float4*)(deg_b + g * 8);
        const float4 d1 = *(const float4*)(deg_b + g * 8 + 4);
        a[4] = (f16x8){
            (_Float16)fmaxf(ld * w0.x + d0.x, 0.f), (_Float16)fmaxf(ld * w0.y + d0.y, 0.f),
            (_Float16)fmaxf(ld * w0.z + d0.z, 0.f), (_Float16)fmaxf(ld * w0.w + d0.w, 0.f),
            (_Float16)fmaxf(ld * w1.x + d1.x, 0.f), (_Float16)fmaxf(ld * w1.y + d1.y, 0.f),
            (_Float16)fmaxf(ld * w1.z + d1.z, 0.f), (_Float16)fmaxf(ld * w1.w + d1.w, 0.f)};
    }

    // ---- proj: 5kk x 8nt MFMAs
    f32x4 Cp[8];
    #pragma unroll
    for (int nt = 0; nt < 8; ++nt) Cp[nt] = (f32x4){0.f, 0.f, 0.f, 0.f};
    #pragma unroll
    for (int kk = 0; kk < 5; ++kk) {
        #pragma unroll
        for (int nt = 0; nt < 8; ++nt) {
            const f16x8 bf = *(const f16x8*)(wprojp + ((nt * 5 + kk) << 9) + lane * 8);
            Cp[nt] = __builtin_amdgcn_mfma_f32_16x16x32_f16(a[kk], bf, Cp[nt], 0, 0, 0);
        }
    }
    #pragma unroll
    for (int nt = 0; nt < 8; ++nt) {
        const int nn = nt * 16 + c;
        const float bb = proj_b[nn];
        #pragma unroll
        for (int r = 0; r < 4; ++r) {
            const int rr = g * 4 + r;
            *(_Float16*)(tb + rr * 256 + ((nn * 2) ^ (rr << 4))) = (_Float16)(Cp[nt][r] + bb);
        }
    }
    TILE_STORE_S(xh, 128)

    // ---- layer-0 qkv from the tile
    f16x8 a2[4];
    #pragma unroll
    for (int kk = 0; kk < 4; ++kk)
        a2[kk] = *(const f16x8*)(tb + c * 256 + ((kk * 64 + g * 16) ^ (c << 4)));
    QKV_PHASE(a2, wq, bqkv)
}

// ---------------------------------------------------------------------------
// Kernel 2: fused out-proj (+fallback+relu) and optional next-layer qkv.
// ---------------------------------------------------------------------------
__global__ __launch_bounds__(256) void projqkv_kernel(
    const _Float16* __restrict__ oh, const int* __restrict__ mask,
    const _Float16* __restrict__ xh_prev,
    const _Float16* __restrict__ wo, const float* __restrict__ bo,
    const _Float16* __restrict__ wq, const float* __restrict__ bqkv,
    _Float16* __restrict__ xh_next,
    _Float16* __restrict__ qh, _Float16* __restrict__ kvh,
    int do_qkv, int n)
{
    __shared__ __align__(16) _Float16 tile[4][16 * 128];
    const int wave = threadIdx.x >> 6;
    const int lane = threadIdx.x & 63;
    const int g = lane >> 4, c = lane & 15;
    const int base = (blockIdx.x * 4 + wave) * 16;
    if (base >= n) return;
    const int arow = min(base + c, n - 1);
    char* const tb = (char*)&tile[wave][0];

    // ---- phase 1: o @ Wo
    f32x4 Cp[8];
    #pragma unroll
    for (int nt = 0; nt < 8; ++nt) Cp[nt] = (f32x4){0.f, 0.f, 0.f, 0.f};
    #pragma unroll
    for (int kk = 0; kk < 4; ++kk) {
        const f16x8 a = *(const f16x8*)(oh + (size_t)arow * 128 + kk * 32 + g * 8);
        #pragma unroll
        for (int nt = 0; nt < 8; ++nt) {
            const f16x8 bf = *(const f16x8*)(wo + ((nt * 4 + kk) << 9) + lane * 8);
            Cp[nt] = __builtin_amdgcn_mfma_f32_16x16x32_f16(a, bf, Cp[nt], 0, 0, 0);
        }
    }
    int mk[4]; int rrow[4];
    #pragma unroll
    for (int r = 0; r < 4; ++r) {
        rrow[r] = min(base + g * 4 + r, n - 1);
        mk[r] = mask[rrow[r]];
    }
    #pragma unroll
    for (int nt = 0; nt < 8; ++nt) {
        const int nn = nt * 16 + c;
        const float bb = bo[nn];
        #pragma unroll
        for (int r = 0; r < 4; ++r) {
            float val = Cp[nt][r] + bb;
            if (!mk[r]) val = (float)xh_prev[(size_t)rrow[r] * 128 + nn];
            val = fmaxf(val, 0.0f);
            const int rr = g * 4 + r;
            *(_Float16*)(tb + rr * 256 + ((nn * 2) ^ (rr << 4))) = (_Float16)val;
        }
    }
    // write x_next coalesced (full 128 cols)
    TILE_STORE_S(xh_next, 128)
    if (!do_qkv) return;

    // ---- phase 2: x_next @ Wqkv (A-frags read from tile BEFORE overwriting it)
    f16x8 a2[4];
    #pragma unroll
    for (int kk = 0; kk < 4; ++kk)
        a2[kk] = *(const f16x8*)(tb + c * 256 + ((kk * 64 + g * 16) ^ (c << 4)));
    QKV_PHASE(a2, wq, bqkv)
}

// ---------------------------------------------------------------------------
// Kernel 3: attention core: scores + softmax + PV.  Writes o (fp16) + mask.
// wave per node-group of 2; all 34 gather words (17 k + 17 v) issued upfront;
// k/v interleaved per node: one contiguous 512B row per context.
// ---------------------------------------------------------------------------
__global__ __launch_bounds__(256) void attn_kernel(
    const _Float16* __restrict__ qh, const _Float16* __restrict__ kvh,
    const int* __restrict__ nbr_idx, const int* __restrict__ nbr_mask,
    _Float16* __restrict__ oh, int* __restrict__ mask_out, int n)
{
    const int wave = threadIdx.x >> 6;
    const int lane = threadIdx.x & 63;
    const float scale = 0.17677669529663687f;   // 1/sqrt(32)
    const int base = (blockIdx.x * 4 + wave) * 2;
    if (base >= n) return;
    const int nbc = min(2, n - base);
    for (int nb = 0; nb < nbc; ++nb) {
        const int node = base + nb;
        const unsigned qq = *(const unsigned*)(qh + (size_t)node * HID + lane * 2);
        const float qx = h_lo(qq), qy = h_hi(qq);
        int valid[17];
        int anyn = 0;
        unsigned kw[17], vw[17];
        #pragma unroll
        for (int c = 0; c < 17; ++c) {
            int cidx;
            if (c == 0) { cidx = node; valid[c] = 1; }
            else {
                cidx = nbr_idx[node * 16 + (c - 1)];
                valid[c] = nbr_mask[node * 16 + (c - 1)];
                anyn |= valid[c];
            }
            const _Float16* kv = kvh + (size_t)cidx * 256;
            kw[c] = *(const unsigned*)(kv + lane * 2);          // k dims (2l,2l+1)
            vw[c] = *(const unsigned*)(kv + 128 + lane * 2);    // v dims (2l,2l+1)
        }
        if (lane == 0) mask_out[node] = anyn;
        float s[17];
        #pragma unroll
        for (int c = 0; c < 17; ++c) {
            float p = qx * h_lo(kw[c]) + qy * h_hi(kw[c]);
            p += __shfl_xor(p, 1);
            p += __shfl_xor(p, 2);
            p += __shfl_xor(p, 4);
            p += __shfl_xor(p, 8);
            s[c] = valid[c] ? p * scale : -1e9f;
        }
        float mx = s[0];
        #pragma unroll
        for (int c = 1; c < 17; ++c) mx = fmaxf(mx, s[c]);
        float sum = 0.0f;
        #pragma unroll
        for (int c = 0; c < 17; ++c) { s[c] = __expf(s[c] - mx); sum += s[c]; }
        const float inv = 1.0f / sum;
        float ox = 0.0f, oy = 0.0f;
        #pragma unroll
        for (int c = 0; c < 17; ++c) {
            const float a = s[c] * inv;
            ox += a * h_lo(vw[c]);
            oy += a * h_hi(vw[c]);
        }
        *(unsigned*)(oh + (size_t)node * HID + lane * 2) = pack2h(ox, oy);
    }
}

// ---------------------------------------------------------------------------
// Kernel 4: edge MLP via fp16 MFMA.
// ---------------------------------------------------------------------------
__global__ __launch_bounds__(256) void edge_mfma_kernel(
    const _Float16* __restrict__ xh,          // [N][128] fp16 final x
    const int* __restrict__ edges,
    const float* __restrict__ edge_feats,
    const _Float16* __restrict__ w1p,         // packed B-frags, 32768
    const _Float16* __restrict__ w2p,         // packed B-frags, 8192
    const float* __restrict__ W1,             // fp32 (rows 256,257 used)
    const float* __restrict__ b1,
    const float* __restrict__ b2,
    const float* __restrict__ W3, const float* __restrict__ b3,
    float* __restrict__ out, int ne)
{
    __shared__ __align__(16) _Float16 h1s[4][16 * 128];
    const int wave = threadIdx.x >> 6;
    const int lane = threadIdx.x & 63;
    const int g = lane >> 4, c = lane & 15;
    const int base = (blockIdx.x * 4 + wave) * 16;
    if (base >= ne) return;

    const int erow = min(base + c, ne - 1);
    const int e0 = edges[erow * 2 + 0];
    const int e1 = edges[erow * 2 + 1];

    // ---- layer 1: [16,256] x [256,128]
    f32x4 C1[8];
    #pragma unroll
    for (int nt = 0; nt < 8; ++nt) C1[nt] = (f32x4){0.f, 0.f, 0.f, 0.f};
    #pragma unroll
    for (int kk = 0; kk < 8; ++kk) {
        const int node = (kk < 4) ? e0 : e1;
        const f16x8 a = *(const f16x8*)(xh + (size_t)node * 128 + (kk & 3) * 32 + g * 8);
        #pragma unroll
        for (int nt = 0; nt < 8; ++nt) {
            const f16x8 bf = *(const f16x8*)(w1p + ((nt * 8 + kk) << 9) + lane * 8);
            C1[nt] = __builtin_amdgcn_mfma_f32_16x16x32_f16(a, bf, C1[nt], 0, 0, 0);
        }
    }

    // ---- epilogue 1: + b1 + ef @ W1[256:258] ; relu ; fp16 -> swizzled LDS
    float ef0[4], ef1[4];
    #pragma unroll
    for (int r = 0; r < 4; ++r) {
        const int m = min(base + g * 4 + r, ne - 1);
        ef0[r] = edge_feats[(size_t)m * 2 + 0];
        ef1[r] = edge_feats[(size_t)m * 2 + 1];
    }
    char* const h1base = (char*)&h1s[wave][0];
    #pragma unroll
    for (int nt = 0; nt < 8; ++nt) {
        const int nn  = nt * 16 + c;
        const float bb  = b1[nn];
        const float wc0 = W1[256 * 128 + nn];
        const float wc1 = W1[257 * 128 + nn];
        #pragma unroll
        for (int r = 0; r < 4; ++r) {
            const int rr = g * 4 + r;
            const float h = fmaxf(C1[nt][r] + bb + ef0[r] * wc0 + ef1[r] * wc1, 0.0f);
            *(_Float16*)(h1base + rr * 256 + ((nn * 2) ^ (rr << 4))) = (_Float16)h;
        }
    }

    // ---- layer 2: [16,128] x [128,64]
    f32x4 C2[4];
    #pragma unroll
    for (int nt = 0; nt < 4; ++nt) C2[nt] = (f32x4){0.f, 0.f, 0.f, 0.f};
    #pragma unroll
    for (int kk = 0; kk < 4; ++kk) {
        const int k0b = kk * 64 + g * 16;
        const f16x8 a = *(const f16x8*)(h1base + c * 256 + (k0b ^ (c << 4)));
        #pragma unroll
        for (int nt = 0; nt < 4; ++nt) {
            const f16x8 bf = *(const f16x8*)(w2p + ((nt * 4 + kk) << 9) + lane * 8);
            C2[nt] = __builtin_amdgcn_mfma_f32_16x16x32_f16(a, bf, C2[nt], 0, 0, 0);
        }
    }

    // ---- layer 3: relu(h2) @ W3 + b3, 16-lane tree reduce
    const float bb3 = b3[0];
    #pragma unroll
    for (int r = 0; r < 4; ++r) {
        float acc = 0.0f;
        #pragma unroll
        for (int nt = 0; nt < 4; ++nt) {
            const int n2 = nt * 16 + c;
            acc += fmaxf(C2[nt][r] + b2[n2], 0.0f) * W3[n2];
        }
        acc += __shfl_xor(acc, 1);
        acc += __shfl_xor(acc, 2);
        acc += __shfl_xor(acc, 4);
        acc += __shfl_xor(acc, 8);
        const int m = base + g * 4 + r;
        if (c == 0 && m < ne) out[m] = acc + bb3;
    }
}

// ---------------------------------------------------------------------------
extern "C" void kernel_launch(void* const* d_in, const int* in_sizes, int n_in,
                              void* d_out, int out_size, void* d_ws, size_t ws_size,
                              hipStream_t stream) {
    const int*   type_idx   = (const int*)d_in[0];
    const int*   cat_idx    = (const int*)d_in[1];
    const int*   nbr_idx    = (const int*)d_in[2];
    const int*   nbr_mask   = (const int*)d_in[3];
    const int*   edges      = (const int*)d_in[4];
    const float* log_deg    = (const float*)d_in[5];
    const float* edge_feats = (const float*)d_in[6];
    const float* type_embed = (const float*)d_in[7];
    const float* cat0       = (const float*)d_in[8];
    const float* cat1       = (const float*)d_in[9];
    const float* deg_W      = (const float*)d_in[10];
    const float* deg_b      = (const float*)d_in[11];
    const float* proj_W     = (const float*)d_in[12];
    const float* proj_b     = (const float*)d_in[13];
    const float* attn_Wqkv  = (const float*)d_in[14];
    const float* attn_bqkv  = (const float*)d_in[15];
    const float* attn_Wo    = (const float*)d_in[16];
    const float* attn_bo    = (const float*)d_in[17];
    const float* eW1        = (const float*)d_in[18];
    const float* eb1        = (const float*)d_in[19];
    const float* eW2        = (const float*)d_in[20];
    const float* eb2        = (const float*)d_in[21];
    const float* eW3        = (const float*)d_in[22];
    const float* eb3        = (const float*)d_in[23];

    const int n  = in_sizes[0];        // N nodes
    const int ne = in_sizes[4] / 2;    // E edges
    float* out = (float*)d_out;

    // fp16 workspace buffers
    _Float16* xhA = (_Float16*)d_ws;                 // n*128
    _Float16* xhB = xhA + (size_t)n * HID;           // n*128
    _Float16* qh  = xhB + (size_t)n * HID;           // n*128
    _Float16* kvh = qh  + (size_t)n * HID;           // n*256 (k|v interleaved)
    _Float16* oh  = kvh + (size_t)n * 256;           // n*128
    _Float16* wpk = oh  + (size_t)n * HID;           // packed weights, 258048 halves
    int* mask = (int*)(wpk + 258048);
    _Float16* wqkvp[3] = {wpk, wpk + 49152, wpk + 98304};
    _Float16* wop[3]   = {wpk + 147456, wpk + 163840, wpk + 180224};
    _Float16* w1p    = wpk + 196608;
    _Float16* w2p    = wpk + 229376;
    _Float16* wprojp = wpk + 237568;

    prep_kernel<<<dim3(1008), dim3(256), 0, stream>>>(
        attn_Wqkv, attn_Wo, eW1, eW2, proj_W, wpk);

    const int gemm_grid = (n + 63) / 64;    // 4 waves x 16 nodes
    const int attn_grid = (n + 7) / 8;      // 4 waves x 2 nodes

    // fused encode + layer-0 qkv
    encode_qkv_kernel<<<dim3(gemm_grid), dim3(256), 0, stream>>>(
        type_idx, cat_idx, log_deg, type_embed, cat0, cat1, deg_W, deg_b,
        wprojp, proj_b, wqkvp[0], attn_bqkv,
        xhA, qh, kvh, n);
    attn_kernel<<<dim3(attn_grid), dim3(256), 0, stream>>>(
        qh, kvh, nbr_idx, nbr_mask, oh, mask, n);

    // layer transitions: (oh,mask,x_prev) -> x_next (+ qkv for next layer)
    projqkv_kernel<<<dim3(gemm_grid), dim3(256), 0, stream>>>(
        oh, mask, xhA, wop[0], attn_bo, wqkvp[1], attn_bqkv + 384,
        xhB, qh, kvh, 1, n);
    attn_kernel<<<dim3(attn_grid), dim3(256), 0, stream>>>(
        qh, kvh, nbr_idx, nbr_mask, oh, mask, n);

    projqkv_kernel<<<dim3(gemm_grid), dim3(256), 0, stream>>>(
        oh, mask, xhB, wop[1], attn_bo + 128, wqkvp[2], attn_bqkv + 768,
        xhA, qh, kvh, 1, n);
    attn_kernel<<<dim3(attn_grid), dim3(256), 0, stream>>>(
        qh, kvh, nbr_idx, nbr_mask, oh, mask, n);

    projqkv_kernel<<<dim3(gemm_grid), dim3(256), 0, stream>>>(
        oh, mask, xhA, wop[2], attn_bo + 256, nullptr, nullptr,
        xhB, nullptr, nullptr, 0, n);

    const int edge_grid = (ne + 63) / 64;   // 4 waves x 16 edges
    edge_mfma_kernel<<<dim3(edge_grid), dim3(256), 0, stream>>>(
        xhB, edges, edge_feats, w1p, w2p, eW1, eb1, eb2, eW3, eb3, out, ne);
}